// Round 11
// baseline (149.392 us; speedup 1.0000x reference)
//
#include <hip/hip_runtime.h>
#include <math.h>

#define BB 64
#define HH 1024
#define VV 32000
#define SRC 128
#define SLSTM 8
#define SCAT 8

typedef __attribute__((ext_vector_type(8))) __bf16 bf16x8;
typedef __attribute__((ext_vector_type(8))) unsigned short ushort8;
typedef __attribute__((ext_vector_type(4))) float f32x4;

__device__ __forceinline__ float sigmoidf_(float x){ return 1.f/(1.f+expf(-x)); }

__device__ __forceinline__ unsigned short f2bf(float f){
    union { float f; unsigned u; } v; v.f = f;
    unsigned r = v.u + 0x7FFFu + ((v.u >> 16) & 1u);   // round-to-nearest-even
    return (unsigned short)(r >> 16);
}

__device__ __forceinline__ void cvt8(const float4& x, const float4& y, unsigned short* dst){
    ushort8 s;
    s[0]=f2bf(x.x); s[1]=f2bf(x.y); s[2]=f2bf(x.z); s[3]=f2bf(x.w);
    s[4]=f2bf(y.x); s[5]=f2bf(y.y); s[6]=f2bf(y.z); s[7]=f2bf(y.w);
    *(ushort8*)dst = s;
}

// ---- 64x128 MFMA tile, 512 threads: 2-deep register prefetch, dbuf LDS ----
template<int NT>
__device__ __forceinline__ void tile_mm(
    const int* tk, const float* A0, const float* A1,
    const float* B0, const float* B1, int K0, int ldb,
    int n0, int kbase,
    unsigned short* AsL, unsigned short* BsL, f32x4* acc)
{
    const int tid = threadIdx.x;
    const int am = tid >> 3, ak = (tid & 7) << 3;
    const int bn = tid >> 2, bk = (tid & 3) << 4;
    const int arow = tk ? tk[am] : am;
    float4 aA[2], bA[4], aB[2], bB[4];

    auto loadG = [&](int t, float4* ar, float4* br){
        int ka = kbase + (t << 6) + ak;
        const float* Ap = (ka < 1024) ? (A0 + (size_t)arow*HH + ka)
                                      : (A1 + (size_t)am*HH + (ka - 1024));
        ar[0] = *(const float4*)(Ap);
        ar[1] = *(const float4*)(Ap + 4);
        int kg = kbase + (t << 6);
        const float* Bp; int kb;
        if (kg < K0) { Bp = B0; kb = kg; } else { Bp = B1; kb = kg - K0; }
        const float* Bq = Bp + (size_t)(n0 + bn) * ldb + kb + bk;
        #pragma unroll
        for (int i = 0; i < 4; ++i) br[i] = *(const float4*)(Bq + i*4);
    };
    auto writeL = [&](int buf, const float4* ar, const float4* br){
        cvt8(ar[0], ar[1], &AsL[buf*4608 + am*72 + ak]);
        cvt8(br[0], br[1], &BsL[buf*9216 + bn*72 + bk]);
        cvt8(br[2], br[3], &BsL[buf*9216 + bn*72 + bk + 8]);
    };

    loadG(0, aA, bA);
    if (NT > 1) loadG(1, aB, bB);
    writeL(0, aA, bA);
    __syncthreads();

    const int lane = tid & 63, w = tid >> 6;
    const int lr = lane >> 4, lc = lane & 15;

    #pragma unroll
    for (int t = 0; t < NT; ++t) {
        const int cur = t & 1;
        if (t + 2 < NT) loadG(t + 2, cur ? aB : aA, cur ? bB : bA);
        #pragma unroll
        for (int ks = 0; ks < 2; ++ks) {
            bf16x8 bF = *(const bf16x8*)&BsL[cur*9216 + (w*16 + lc)*72 + ks*32 + lr*8];
            #pragma unroll
            for (int fm = 0; fm < 4; ++fm) {
                bf16x8 aF = *(const bf16x8*)&AsL[cur*4608 + (fm*16 + lc)*72 + ks*32 + lr*8];
                acc[fm] = __builtin_amdgcn_mfma_f32_16x16x32_bf16(aF, bF, acc[fm], 0, 0, 0);
            }
        }
        if (t + 1 < NT) {
            writeL(cur ^ 1, cur ? aA : aB, cur ? bA : bB);
            __syncthreads();
        }
    }
}

// ============ split-K weight GEMM (+ optional u_e side-blocks), 512 threads ============
// grid = (N/128, 8 [+1 if EXTRA]); kChunk=256; raw partials to C + y*64*N.
// EXTRA==1: y==8, x<16 -> u_e = (attn_W^T v)[1024:2048]
template<int GATHER, int EXTRA>
__global__ __launch_bounds__(512)
void gemm_bf(const int* __restrict__ tokens,
             const float* __restrict__ A0, const float* __restrict__ A1,
             const float* __restrict__ B0, const float* __restrict__ B1,
             int K0, int ldb, int N, float* __restrict__ C,
             const float* __restrict__ xa, const float* __restrict__ xb,
             float* __restrict__ xo)
{
    __shared__ __align__(16) unsigned short As[2*4608];
    __shared__ __align__(16) unsigned short Bs[2*9216];
    const int tid = threadIdx.x;

    if (EXTRA && blockIdx.y >= 8) {
        // u_e[k] = sum_h attn_v[h]*attn_W[h][1024+k]  (h/bias score terms cancel)
        if (blockIdx.x >= 16) return;
        float4 (*red4)[16] = (float4 (*)[16])As;
        int kq = tid & 15, hp = tid >> 4;       // hp 0..31
        int k = 1024 + blockIdx.x*64 + kq*4;
        float4 s4 = {0.f,0.f,0.f,0.f};
        for (int h = hp; h < HH; h += 32) {
            float vh = xb[h];
            float4 wv = *(const float4*)&xa[(size_t)h*2048 + k];
            s4.x = fmaf(vh, wv.x, s4.x); s4.y = fmaf(vh, wv.y, s4.y);
            s4.z = fmaf(vh, wv.z, s4.z); s4.w = fmaf(vh, wv.w, s4.w);
        }
        red4[hp][kq] = s4;
        __syncthreads();
        if (tid < 16) {
            float4 t4 = {0.f,0.f,0.f,0.f};
            #pragma unroll
            for (int i = 0; i < 32; ++i) {
                float4 rv = red4[i][tid];
                t4.x += rv.x; t4.y += rv.y; t4.z += rv.z; t4.w += rv.w;
            }
            *(float4*)&xo[blockIdx.x*64 + tid*4] = t4;
        }
        return;
    }

    f32x4 acc[4] = {};
    const int n0 = blockIdx.x * 128;
    tile_mm<4>(GATHER ? tokens : nullptr, A0, A1, B0, B1, K0, ldb,
               n0, blockIdx.y * 256, As, Bs, acc);
    float* Cp = C + (size_t)blockIdx.y * 64 * N;
    const int lane = tid & 63, w = tid >> 6;
    const int lr = lane >> 4, lc = lane & 15;
    const int n = n0 + w*16 + lc;
    #pragma unroll
    for (int fm = 0; fm < 4; ++fm)
        #pragma unroll
        for (int r = 0; r < 4; ++r)
            Cp[(size_t)(fm*16 + lr*4 + r)*N + n] = acc[fm][r];
}

// ====== out-projection with INLINE h_c = tanh(concat_b + sum8 catP) on the A-path ======
// 250 blocks x 512 threads; per-block row (max, expsum) partials fused in epilogue.
__global__ __launch_bounds__(512)
void out_gemm(const float* __restrict__ catP, const float* __restrict__ cbias,
              const float* __restrict__ W, const float* __restrict__ bias,
              float* __restrict__ logits, float2* __restrict__ ms)
{
    __shared__ __align__(16) unsigned short As[2*4608];
    __shared__ __align__(16) unsigned short Bs[2*9216];
    __shared__ float wm[8][64], wsum[8][64];
    const int tid = threadIdx.x;
    const int n0 = blockIdx.x * 128;
    const int am = tid >> 3, ak = (tid & 7) << 3;   // A: row, 8-float k chunk
    const int bn = tid >> 2, bk = (tid & 3) << 4;   // B: row, 16-float k chunk

    f32x4 acc[4] = {};
    float4 bA[4], bB[4];          // B staging, 2 sets
    float4 gA[16];                // catP slices for one A tile (8 slices x 2 float4)
    float4 cb0, cb1;

    auto loadB = [&](int t, float4* br){
        const float* Wp = W + (size_t)(n0 + bn)*HH + (t << 6) + bk;
        #pragma unroll
        for (int i = 0; i < 4; ++i) br[i] = *(const float4*)(Wp + i*4);
    };
    auto loadA = [&](int t){
        int k = (t << 6) + ak;
        #pragma unroll
        for (int s = 0; s < 8; ++s) {
            const float* p = catP + ((size_t)s << 16) + am*HH + k;
            gA[2*s]   = *(const float4*)(p);
            gA[2*s+1] = *(const float4*)(p + 4);
        }
        cb0 = *(const float4*)(cbias + k);
        cb1 = *(const float4*)(cbias + k + 4);
    };
    auto writeB = [&](int buf, const float4* br){
        cvt8(br[0], br[1], &Bs[buf*9216 + bn*72 + bk]);
        cvt8(br[2], br[3], &Bs[buf*9216 + bn*72 + bk + 8]);
    };
    auto writeA = [&](int buf){
        float4 f0 = cb0, f1 = cb1;
        #pragma unroll
        for (int s = 0; s < 8; ++s) {
            f0.x += gA[2*s].x;   f0.y += gA[2*s].y;
            f0.z += gA[2*s].z;   f0.w += gA[2*s].w;
            f1.x += gA[2*s+1].x; f1.y += gA[2*s+1].y;
            f1.z += gA[2*s+1].z; f1.w += gA[2*s+1].w;
        }
        f0.x = tanhf(f0.x); f0.y = tanhf(f0.y); f0.z = tanhf(f0.z); f0.w = tanhf(f0.w);
        f1.x = tanhf(f1.x); f1.y = tanhf(f1.y); f1.z = tanhf(f1.z); f1.w = tanhf(f1.w);
        cvt8(f0, f1, &As[buf*4608 + am*72 + ak]);
    };

    loadB(0, bA); loadB(1, bB); loadA(0);
    writeA(0); writeB(0, bA);
    __syncthreads();

    const int lane = tid & 63, w = tid >> 6;
    const int lr = lane >> 4, lc = lane & 15;

    #pragma unroll
    for (int t = 0; t < 16; ++t) {
        const int cur = t & 1;
        if (t + 1 < 16) loadA(t + 1);                       // L2 loads, land during MFMA
        if (t + 2 < 16) loadB(t + 2, cur ? bB : bA);        // HBM stream, 2-deep
        #pragma unroll
        for (int ks = 0; ks < 2; ++ks) {
            bf16x8 bF = *(const bf16x8*)&Bs[cur*9216 + (w*16 + lc)*72 + ks*32 + lr*8];
            #pragma unroll
            for (int fm = 0; fm < 4; ++fm) {
                bf16x8 aF = *(const bf16x8*)&As[cur*4608 + (fm*16 + lc)*72 + ks*32 + lr*8];
                acc[fm] = __builtin_amdgcn_mfma_f32_16x16x32_bf16(aF, bF, acc[fm], 0, 0, 0);
            }
        }
        if (t + 1 < 16) {
            writeB(cur ^ 1, cur ? bA : bB);
            writeA(cur ^ 1);
            __syncthreads();
        }
    }

    const int n = n0 + w*16 + lc;
    const float bv = bias[n];
    #pragma unroll
    for (int fm = 0; fm < 4; ++fm) {
        #pragma unroll
        for (int r = 0; r < 4; ++r) {
            float v = acc[fm][r] + bv;
            logits[(size_t)(fm*16 + lr*4 + r)*VV + n] = v;
            float mx = v;
            #pragma unroll
            for (int o = 1; o < 16; o <<= 1) mx = fmaxf(mx, __shfl_xor(mx, o));
            float se = expf(v - mx);
            #pragma unroll
            for (int o = 1; o < 16; o <<= 1) se += __shfl_xor(se, o);
            if (lc == 0) { wm[w][fm*16 + lr*4 + r] = mx;
                           wsum[w][fm*16 + lr*4 + r] = se; }
        }
    }
    __syncthreads();
    if (tid < 64) {
        float M = wm[0][tid];
        #pragma unroll
        for (int i = 1; i < 8; ++i) M = fmaxf(M, wm[i][tid]);
        float S = 0.f;
        #pragma unroll
        for (int i = 0; i < 8; ++i) S += wsum[i][tid] * expf(wm[i][tid] - M);
        ms[blockIdx.x*64 + tid] = make_float2(M, S);
    }
}

// ------- LSTM pointwise (512 thr, 128 blocks) + optional full-attention side-blocks -------
// WITH_ATTN: blocks 128..191 each own batch-row b: scores -> softmax -> context,
// with the context pass re-reading enc from L2 (512 KB/block just read in scores).
template<int WITH_ATTN>
__global__ __launch_bounds__(512)
void lstm_attn(const float* __restrict__ gates,   // [SLSTM][64][4096] raw partials
               const float* __restrict__ bih, const float* __restrict__ bhh,
               const float* __restrict__ c0,
               float* __restrict__ hn, float* __restrict__ cn,
               float* __restrict__ hout,
               const float* __restrict__ u_e, const float* __restrict__ enc,
               float* __restrict__ ctx)
{
    const int bid = blockIdx.x, tid = threadIdx.x;
    if (WITH_ATTN && bid >= 128) {
        __shared__ float wl[SRC];
        const int b = bid - 128;
        const int w = tid >> 6, lane = tid & 63;
        // scores[l] = u_e . enc[l,b,:]  (wave w owns l = 16w..16w+15)
        #pragma unroll
        for (int i = 0; i < 16; ++i) {
            int l = w*16 + i;
            const float* e = enc + (size_t)(l*BB + b)*HH;
            float s = 0.f;
            #pragma unroll
            for (int t = 0; t < 16; ++t)
                s = fmaf(u_e[lane + 64*t], e[lane + 64*t], s);
            #pragma unroll
            for (int o = 32; o > 0; o >>= 1) s += __shfl_xor(s, o);
            if (lane == 0) wl[l] = s;
        }
        __syncthreads();
        float m = -INFINITY;
        #pragma unroll 8
        for (int l = 0; l < SRC; ++l) m = fmaxf(m, wl[l]);
        float sum = 0.f;
        #pragma unroll 8
        for (int l = 0; l < SRC; ++l) sum += expf(wl[l] - m);
        float inv = 1.f / sum;
        __syncthreads();
        if (tid < SRC) wl[tid] = expf(wl[tid] - m) * inv;
        __syncthreads();
        float a0 = 0.f, a1 = 0.f;
        for (int l = 0; l < SRC; ++l) {
            const float* e = enc + (size_t)(l*BB + b)*HH;
            float wv = wl[l];
            a0 = fmaf(wv, e[tid], a0);          // L2-hot re-read
            a1 = fmaf(wv, e[tid + 512], a1);
        }
        ctx[b*HH + tid] = a0;
        ctx[b*HH + tid + 512] = a1;
        return;
    }
    int idx = (bid << 9) + tid;          // 0..65535
    int b = idx >> 10, k = idx & 1023;
    const float* g = gates + b*4096;
    float ig = bih[k]        + bhh[k];
    float fg = bih[1024 + k] + bhh[1024 + k];
    float gg = bih[2048 + k] + bhh[2048 + k];
    float og = bih[3072 + k] + bhh[3072 + k];
    #pragma unroll
    for (int s = 0; s < SLSTM; ++s) {
        const float* gs = g + s*BB*4096;
        ig += gs[k];
        fg += gs[1024 + k];
        gg += gs[2048 + k];
        og += gs[3072 + k];
    }
    float c = sigmoidf_(fg)*c0[b*HH + k] + sigmoidf_(ig)*tanhf(gg);
    float h = sigmoidf_(og)*tanhf(c);
    cn[b*HH + k] = c;
    hn[b*HH + k] = h;
    hout[b*HH + k] = h;
}

// ------- merge 250 per-block (m,s) partials -> lse[b]; subtract in place -------
__global__ __launch_bounds__(256)
void sub_final(float* __restrict__ logp, const float2* __restrict__ ms)
{
    __shared__ float2 red[256];
    int b = blockIdx.y;
    float m = -INFINITY, s = 0.f;
    if (threadIdx.x < 250) {
        float2 p = ms[threadIdx.x*64 + b];
        m = p.x; s = p.y;
    }
    red[threadIdx.x] = make_float2(m, s);
    __syncthreads();
    for (int o = 128; o > 0; o >>= 1) {
        if (threadIdx.x < o) {
            float2 a = red[threadIdx.x], c = red[threadIdx.x + o];
            float M = fmaxf(a.x, c.x);
            float S = a.y * expf(a.x - M) + c.y * expf(c.x - M);
            red[threadIdx.x] = make_float2(M, S);
        }
        __syncthreads();
    }
    float lse = red[0].x + logf(red[0].y);
    int i = blockIdx.x*256 + threadIdx.x;       // over 8000 float4
    if (i < 8000) {
        float4* p = (float4*)(logp + (size_t)b*VV);
        float4 v = p[i];
        v.x -= lse; v.y -= lse; v.z -= lse; v.w -= lse;
        p[i] = v;
    }
}

// ================================================================
extern "C" void kernel_launch(void* const* d_in, const int* in_sizes, int n_in,
                              void* d_out, int out_size, void* d_ws, size_t ws_size,
                              hipStream_t stream)
{
    const int*   tokens   = (const int*)  d_in[0];
    const float* h0       = (const float*)d_in[1];
    const float* c0       = (const float*)d_in[2];
    const float* enc      = (const float*)d_in[3];
    const float* emb      = (const float*)d_in[4];
    const float* W_ih     = (const float*)d_in[5];
    const float* W_hh     = (const float*)d_in[6];
    const float* b_ih     = (const float*)d_in[7];
    const float* b_hh     = (const float*)d_in[8];
    const float* attn_W   = (const float*)d_in[9];
    const float* attn_v   = (const float*)d_in[11];
    const float* concat_W = (const float*)d_in[12];
    const float* concat_b = (const float*)d_in[13];
    const float* out_W    = (const float*)d_in[14];
    const float* out_b    = (const float*)d_in[15];

    float* out  = (float*)d_out;
    float* logp = out;                      // [64, 32000]
    float* h_n  = out + (size_t)BB*VV;      // [2, 64, 1024]
    float* c_n  = h_n + 2*BB*HH;            // [2, 64, 1024]

    // workspace layout (floats)
    float* ws     = (float*)d_ws;
    float* gates  = ws;                       // [SLSTM=8][64][4096] partials
    float* catP   = gates + SLSTM*262144;     // [SCAT=8][64][1024] partials
    float* h1     = catP  + SCAT*65536;       // [64][1024]
    float* h_top  = h1    + 65536;            // [64][1024]
    float* ctx    = h_top + 65536;            // [64][1024]
    float* u_e    = ctx   + 65536;            // [1024]
    float2* ms    = (float2*)(u_e + 1024);    // [250][64] (m, s)

    // 1) LSTM L0 GEMM (A = [emb[tok] ; h0[0]] gathered inline) + u_e side-blocks
    gemm_bf<1,1><<<dim3(32, 9), 512, 0, stream>>>(
        tokens, emb, h0, W_ih, W_hh, 1024, 1024, 4096, gates,
        attn_W, attn_v, u_e);

    // 2) LSTM L0 pointwise + full attention (scores->softmax->context, enc L2-hot)
    lstm_attn<1><<<192, 512, 0, stream>>>(gates, b_ih, b_hh, c0,
                                          h_n, c_n, h1, u_e, enc, ctx);

    // 3) LSTM L1 GEMM (A = [h1 ; h0[1]]) — pure
    gemm_bf<0,0><<<dim3(32, 8), 512, 0, stream>>>(
        nullptr, h1, h0 + BB*HH,
        W_ih + (size_t)4096*1024, W_hh + (size_t)4096*1024, 1024, 1024,
        4096, gates, nullptr, nullptr, nullptr);

    // 4) LSTM L1 pointwise
    lstm_attn<0><<<128, 512, 0, stream>>>(gates, b_ih + 4096, b_hh + 4096, c0 + BB*HH,
                                          h_n + BB*HH, c_n + BB*HH, h_top,
                                          nullptr, nullptr, nullptr);

    // 5) concat GEMM (A = [ctx ; h_top], K=2048) -> catP partials
    gemm_bf<0,0><<<dim3(8, 8), 512, 0, stream>>>(
        nullptr, ctx, h_top, concat_W, nullptr, 1 << 30, 2048,
        1024, catP, nullptr, nullptr, nullptr);

    // 6) out-projection with inline h_c = tanh(concat_b + sum catP) on the A-path
    out_gemm<<<250, 512, 0, stream>>>(catP, concat_b, out_W, out_b, logp, ms);

    // 7) merge partials -> lse, subtract in place
    sub_final<<<dim3(32, 64), 256, 0, stream>>>(logp, ms);
}

// Round 12
// 145.541 us; speedup vs baseline: 1.0265x; 1.0265x over previous
//
#include <hip/hip_runtime.h>
#include <math.h>

#define BB 64
#define HH 1024
#define VV 32000
#define SRC 128
#define SLSTM 8
#define SCAT 8

typedef __attribute__((ext_vector_type(8))) __bf16 bf16x8;
typedef __attribute__((ext_vector_type(8))) unsigned short ushort8;
typedef __attribute__((ext_vector_type(4))) float f32x4;

__device__ __forceinline__ float sigmoidf_(float x){ return 1.f/(1.f+expf(-x)); }

__device__ __forceinline__ unsigned short f2bf(float f){
    union { float f; unsigned u; } v; v.f = f;
    unsigned r = v.u + 0x7FFFu + ((v.u >> 16) & 1u);   // round-to-nearest-even
    return (unsigned short)(r >> 16);
}

__device__ __forceinline__ void cvt8(const float4& x, const float4& y, unsigned short* dst){
    ushort8 s;
    s[0]=f2bf(x.x); s[1]=f2bf(x.y); s[2]=f2bf(x.z); s[3]=f2bf(x.w);
    s[4]=f2bf(y.x); s[5]=f2bf(y.y); s[6]=f2bf(y.z); s[7]=f2bf(y.w);
    *(ushort8*)dst = s;
}

// ---- 64x128 MFMA tile, 512 threads: 2-deep register prefetch, dbuf LDS ----
template<int NT>
__device__ __forceinline__ void tile_mm(
    const int* tk, const float* A0, const float* A1,
    const float* B0, const float* B1, int K0, int ldb,
    int n0, int kbase,
    unsigned short* AsL, unsigned short* BsL, f32x4* acc)
{
    const int tid = threadIdx.x;
    const int am = tid >> 3, ak = (tid & 7) << 3;
    const int bn = tid >> 2, bk = (tid & 3) << 4;
    const int arow = tk ? tk[am] : am;
    float4 aA[2], bA[4], aB[2], bB[4];

    auto loadG = [&](int t, float4* ar, float4* br){
        int ka = kbase + (t << 6) + ak;
        const float* Ap = (ka < 1024) ? (A0 + (size_t)arow*HH + ka)
                                      : (A1 + (size_t)am*HH + (ka - 1024));
        ar[0] = *(const float4*)(Ap);
        ar[1] = *(const float4*)(Ap + 4);
        int kg = kbase + (t << 6);
        const float* Bp; int kb;
        if (kg < K0) { Bp = B0; kb = kg; } else { Bp = B1; kb = kg - K0; }
        const float* Bq = Bp + (size_t)(n0 + bn) * ldb + kb + bk;
        #pragma unroll
        for (int i = 0; i < 4; ++i) br[i] = *(const float4*)(Bq + i*4);
    };
    auto writeL = [&](int buf, const float4* ar, const float4* br){
        cvt8(ar[0], ar[1], &AsL[buf*4608 + am*72 + ak]);
        cvt8(br[0], br[1], &BsL[buf*9216 + bn*72 + bk]);
        cvt8(br[2], br[3], &BsL[buf*9216 + bn*72 + bk + 8]);
    };

    loadG(0, aA, bA);
    if (NT > 1) loadG(1, aB, bB);
    writeL(0, aA, bA);
    __syncthreads();

    const int lane = tid & 63, w = tid >> 6;
    const int lr = lane >> 4, lc = lane & 15;

    #pragma unroll
    for (int t = 0; t < NT; ++t) {
        const int cur = t & 1;
        if (t + 2 < NT) loadG(t + 2, cur ? aB : aA, cur ? bB : bA);
        #pragma unroll
        for (int ks = 0; ks < 2; ++ks) {
            bf16x8 bF = *(const bf16x8*)&BsL[cur*9216 + (w*16 + lc)*72 + ks*32 + lr*8];
            #pragma unroll
            for (int fm = 0; fm < 4; ++fm) {
                bf16x8 aF = *(const bf16x8*)&AsL[cur*4608 + (fm*16 + lc)*72 + ks*32 + lr*8];
                acc[fm] = __builtin_amdgcn_mfma_f32_16x16x32_bf16(aF, bF, acc[fm], 0, 0, 0);
            }
        }
        if (t + 1 < NT) {
            writeL(cur ^ 1, cur ? aA : aB, cur ? bA : bB);
            __syncthreads();
        }
    }
}

// ============ split-K weight GEMM (+ optional u_e side-blocks), 512 threads ============
// grid = (N/128, 8 [+1 if EXTRA]); kChunk=256; raw partials to C + y*64*N.
// EXTRA==1: y==8, x<16 -> u_e = (attn_W^T v)[1024:2048]
template<int GATHER, int EXTRA>
__global__ __launch_bounds__(512)
void gemm_bf(const int* __restrict__ tokens,
             const float* __restrict__ A0, const float* __restrict__ A1,
             const float* __restrict__ B0, const float* __restrict__ B1,
             int K0, int ldb, int N, float* __restrict__ C,
             const float* __restrict__ xa, const float* __restrict__ xb,
             float* __restrict__ xo)
{
    __shared__ __align__(16) unsigned short As[2*4608];
    __shared__ __align__(16) unsigned short Bs[2*9216];
    const int tid = threadIdx.x;

    if (EXTRA && blockIdx.y >= 8) {
        // u_e[k] = sum_h attn_v[h]*attn_W[h][1024+k]  (h/bias score terms cancel)
        if (blockIdx.x >= 16) return;
        float4 (*red4)[16] = (float4 (*)[16])As;
        int kq = tid & 15, hp = tid >> 4;       // hp 0..31
        int k = 1024 + blockIdx.x*64 + kq*4;
        float4 s4 = {0.f,0.f,0.f,0.f};
        for (int h = hp; h < HH; h += 32) {
            float vh = xb[h];
            float4 wv = *(const float4*)&xa[(size_t)h*2048 + k];
            s4.x = fmaf(vh, wv.x, s4.x); s4.y = fmaf(vh, wv.y, s4.y);
            s4.z = fmaf(vh, wv.z, s4.z); s4.w = fmaf(vh, wv.w, s4.w);
        }
        red4[hp][kq] = s4;
        __syncthreads();
        if (tid < 16) {
            float4 t4 = {0.f,0.f,0.f,0.f};
            #pragma unroll
            for (int i = 0; i < 32; ++i) {
                float4 rv = red4[i][tid];
                t4.x += rv.x; t4.y += rv.y; t4.z += rv.z; t4.w += rv.w;
            }
            *(float4*)&xo[blockIdx.x*64 + tid*4] = t4;
        }
        return;
    }

    f32x4 acc[4] = {};
    const int n0 = blockIdx.x * 128;
    tile_mm<4>(GATHER ? tokens : nullptr, A0, A1, B0, B1, K0, ldb,
               n0, blockIdx.y * 256, As, Bs, acc);
    float* Cp = C + (size_t)blockIdx.y * 64 * N;
    const int lane = tid & 63, w = tid >> 6;
    const int lr = lane >> 4, lc = lane & 15;
    const int n = n0 + w*16 + lc;
    #pragma unroll
    for (int fm = 0; fm < 4; ++fm)
        #pragma unroll
        for (int r = 0; r < 4; ++r)
            Cp[(size_t)(fm*16 + lr*4 + r)*N + n] = acc[fm][r];
}

// ====== out-projection with INLINE h_c = tanh(concat_b + sum8 catP) on the A-path ======
// 250 blocks x 512 threads; per-block row (max, expsum) partials fused in epilogue.
__global__ __launch_bounds__(512)
void out_gemm(const float* __restrict__ catP, const float* __restrict__ cbias,
              const float* __restrict__ W, const float* __restrict__ bias,
              float* __restrict__ logits, float2* __restrict__ ms)
{
    __shared__ __align__(16) unsigned short As[2*4608];
    __shared__ __align__(16) unsigned short Bs[2*9216];
    __shared__ float wm[8][64], wsum[8][64];
    const int tid = threadIdx.x;
    const int n0 = blockIdx.x * 128;
    const int am = tid >> 3, ak = (tid & 7) << 3;   // A: row, 8-float k chunk
    const int bn = tid >> 2, bk = (tid & 3) << 4;   // B: row, 16-float k chunk

    f32x4 acc[4] = {};
    float4 bA[4], bB[4];          // B staging, 2 sets
    float4 gA[16];                // catP slices for one A tile (8 slices x 2 float4)
    float4 cb0, cb1;

    auto loadB = [&](int t, float4* br){
        const float* Wp = W + (size_t)(n0 + bn)*HH + (t << 6) + bk;
        #pragma unroll
        for (int i = 0; i < 4; ++i) br[i] = *(const float4*)(Wp + i*4);
    };
    auto loadA = [&](int t){
        int k = (t << 6) + ak;
        #pragma unroll
        for (int s = 0; s < 8; ++s) {
            const float* p = catP + ((size_t)s << 16) + am*HH + k;
            gA[2*s]   = *(const float4*)(p);
            gA[2*s+1] = *(const float4*)(p + 4);
        }
        cb0 = *(const float4*)(cbias + k);
        cb1 = *(const float4*)(cbias + k + 4);
    };
    auto writeB = [&](int buf, const float4* br){
        cvt8(br[0], br[1], &Bs[buf*9216 + bn*72 + bk]);
        cvt8(br[2], br[3], &Bs[buf*9216 + bn*72 + bk + 8]);
    };
    auto writeA = [&](int buf){
        float4 f0 = cb0, f1 = cb1;
        #pragma unroll
        for (int s = 0; s < 8; ++s) {
            f0.x += gA[2*s].x;   f0.y += gA[2*s].y;
            f0.z += gA[2*s].z;   f0.w += gA[2*s].w;
            f1.x += gA[2*s+1].x; f1.y += gA[2*s+1].y;
            f1.z += gA[2*s+1].z; f1.w += gA[2*s+1].w;
        }
        f0.x = tanhf(f0.x); f0.y = tanhf(f0.y); f0.z = tanhf(f0.z); f0.w = tanhf(f0.w);
        f1.x = tanhf(f1.x); f1.y = tanhf(f1.y); f1.z = tanhf(f1.z); f1.w = tanhf(f1.w);
        cvt8(f0, f1, &As[buf*4608 + am*72 + ak]);
    };

    loadB(0, bA); loadB(1, bB); loadA(0);
    writeA(0); writeB(0, bA);
    __syncthreads();

    const int lane = tid & 63, w = tid >> 6;
    const int lr = lane >> 4, lc = lane & 15;

    #pragma unroll
    for (int t = 0; t < 16; ++t) {
        const int cur = t & 1;
        if (t + 1 < 16) loadA(t + 1);                       // L2 loads, land during MFMA
        if (t + 2 < 16) loadB(t + 2, cur ? bB : bA);        // HBM stream, 2-deep
        #pragma unroll
        for (int ks = 0; ks < 2; ++ks) {
            bf16x8 bF = *(const bf16x8*)&Bs[cur*9216 + (w*16 + lc)*72 + ks*32 + lr*8];
            #pragma unroll
            for (int fm = 0; fm < 4; ++fm) {
                bf16x8 aF = *(const bf16x8*)&As[cur*4608 + (fm*16 + lc)*72 + ks*32 + lr*8];
                acc[fm] = __builtin_amdgcn_mfma_f32_16x16x32_bf16(aF, bF, acc[fm], 0, 0, 0);
            }
        }
        if (t + 1 < 16) {
            writeB(cur ^ 1, cur ? bA : bB);
            writeA(cur ^ 1);
            __syncthreads();
        }
    }

    const int n = n0 + w*16 + lc;
    const float bv = bias[n];
    #pragma unroll
    for (int fm = 0; fm < 4; ++fm) {
        #pragma unroll
        for (int r = 0; r < 4; ++r) {
            float v = acc[fm][r] + bv;
            logits[(size_t)(fm*16 + lr*4 + r)*VV + n] = v;
            float mx = v;
            #pragma unroll
            for (int o = 1; o < 16; o <<= 1) mx = fmaxf(mx, __shfl_xor(mx, o));
            float se = expf(v - mx);
            #pragma unroll
            for (int o = 1; o < 16; o <<= 1) se += __shfl_xor(se, o);
            if (lc == 0) { wm[w][fm*16 + lr*4 + r] = mx;
                           wsum[w][fm*16 + lr*4 + r] = se; }
        }
    }
    __syncthreads();
    if (tid < 64) {
        float M = wm[0][tid];
        #pragma unroll
        for (int i = 1; i < 8; ++i) M = fmaxf(M, wm[i][tid]);
        float S = 0.f;
        #pragma unroll
        for (int i = 0; i < 8; ++i) S += wsum[i][tid] * expf(wm[i][tid] - M);
        ms[blockIdx.x*64 + tid] = make_float2(M, S);
    }
}

// ------- LSTM pointwise (512 thr, 128 blocks) + optional full-attention side-blocks -------
// WITH_ATTN: blocks 128..191 each own batch-row b: scores -> softmax -> context,
// with the context pass re-reading enc from L2 (512 KB/block just read in scores).
template<int WITH_ATTN>
__global__ __launch_bounds__(512)
void lstm_attn(const float* __restrict__ gates,   // [SLSTM][64][4096] raw partials
               const float* __restrict__ bih, const float* __restrict__ bhh,
               const float* __restrict__ c0,
               float* __restrict__ hn, float* __restrict__ cn,
               float* __restrict__ hout,
               const float* __restrict__ u_e, const float* __restrict__ enc,
               float* __restrict__ ctx)
{
    const int bid = blockIdx.x, tid = threadIdx.x;
    if (WITH_ATTN && bid >= 128) {
        __shared__ float wl[SRC];
        const int b = bid - 128;
        const int w = tid >> 6, lane = tid & 63;
        // scores[l] = u_e . enc[l,b,:]  (wave w owns l = 16w..16w+15)
        #pragma unroll
        for (int i = 0; i < 16; ++i) {
            int l = w*16 + i;
            const float* e = enc + (size_t)(l*BB + b)*HH;
            float s = 0.f;
            #pragma unroll
            for (int t = 0; t < 16; ++t)
                s = fmaf(u_e[lane + 64*t], e[lane + 64*t], s);
            #pragma unroll
            for (int o = 32; o > 0; o >>= 1) s += __shfl_xor(s, o);
            if (lane == 0) wl[l] = s;
        }
        __syncthreads();
        float m = -INFINITY;
        #pragma unroll 8
        for (int l = 0; l < SRC; ++l) m = fmaxf(m, wl[l]);
        float sum = 0.f;
        #pragma unroll 8
        for (int l = 0; l < SRC; ++l) sum += expf(wl[l] - m);
        float inv = 1.f / sum;
        __syncthreads();
        if (tid < SRC) wl[tid] = expf(wl[tid] - m) * inv;
        __syncthreads();
        float a0 = 0.f, a1 = 0.f;
        for (int l = 0; l < SRC; ++l) {
            const float* e = enc + (size_t)(l*BB + b)*HH;
            float wv = wl[l];
            a0 = fmaf(wv, e[tid], a0);          // L2-hot re-read
            a1 = fmaf(wv, e[tid + 512], a1);
        }
        ctx[b*HH + tid] = a0;
        ctx[b*HH + tid + 512] = a1;
        return;
    }
    int idx = (bid << 9) + tid;          // 0..65535
    int b = idx >> 10, k = idx & 1023;
    const float* g = gates + b*4096;
    float ig = bih[k]        + bhh[k];
    float fg = bih[1024 + k] + bhh[1024 + k];
    float gg = bih[2048 + k] + bhh[2048 + k];
    float og = bih[3072 + k] + bhh[3072 + k];
    #pragma unroll
    for (int s = 0; s < SLSTM; ++s) {
        const float* gs = g + s*BB*4096;
        ig += gs[k];
        fg += gs[1024 + k];
        gg += gs[2048 + k];
        og += gs[3072 + k];
    }
    float c = sigmoidf_(fg)*c0[b*HH + k] + sigmoidf_(ig)*tanhf(gg);
    float h = sigmoidf_(og)*tanhf(c);
    cn[b*HH + k] = c;
    hn[b*HH + k] = h;
    hout[b*HH + k] = h;
}

// ------- merge 250 per-block (m,s) partials -> lse[b]; subtract in place -------
__global__ __launch_bounds__(256)
void sub_final(float* __restrict__ logp, const float2* __restrict__ ms)
{
    __shared__ float2 red[256];
    int b = blockIdx.y;
    float m = -INFINITY, s = 0.f;
    if (threadIdx.x < 250) {
        float2 p = ms[threadIdx.x*64 + b];
        m = p.x; s = p.y;
    }
    red[threadIdx.x] = make_float2(m, s);
    __syncthreads();
    for (int o = 128; o > 0; o >>= 1) {
        if (threadIdx.x < o) {
            float2 a = red[threadIdx.x], c = red[threadIdx.x + o];
            float M = fmaxf(a.x, c.x);
            float S = a.y * expf(a.x - M) + c.y * expf(c.x - M);
            red[threadIdx.x] = make_float2(M, S);
        }
        __syncthreads();
    }
    float lse = red[0].x + logf(red[0].y);
    int i = blockIdx.x*256 + threadIdx.x;       // over 8000 float4
    if (i < 8000) {
        float4* p = (float4*)(logp + (size_t)b*VV);
        float4 v = p[i];
        v.x -= lse; v.y -= lse; v.z -= lse; v.w -= lse;
        p[i] = v;
    }
}

// ================================================================
extern "C" void kernel_launch(void* const* d_in, const int* in_sizes, int n_in,
                              void* d_out, int out_size, void* d_ws, size_t ws_size,
                              hipStream_t stream)
{
    const int*   tokens   = (const int*)  d_in[0];
    const float* h0       = (const float*)d_in[1];
    const float* c0       = (const float*)d_in[2];
    const float* enc      = (const float*)d_in[3];
    const float* emb      = (const float*)d_in[4];
    const float* W_ih     = (const float*)d_in[5];
    const float* W_hh     = (const float*)d_in[6];
    const float* b_ih     = (const float*)d_in[7];
    const float* b_hh     = (const float*)d_in[8];
    const float* attn_W   = (const float*)d_in[9];
    const float* attn_v   = (const float*)d_in[11];
    const float* concat_W = (const float*)d_in[12];
    const float* concat_b = (const float*)d_in[13];
    const float* out_W    = (const float*)d_in[14];
    const float* out_b    = (const float*)d_in[15];

    float* out  = (float*)d_out;
    float* logp = out;                      // [64, 32000]
    float* h_n  = out + (size_t)BB*VV;      // [2, 64, 1024]
    float* c_n  = h_n + 2*BB*HH;            // [2, 64, 1024]

    // workspace layout (floats)
    float* ws     = (float*)d_ws;
    float* gates  = ws;                       // [SLSTM=8][64][4096] partials
    float* catP   = gates + SLSTM*262144;     // [SCAT=8][64][1024] partials
    float* h1     = catP  + SCAT*65536;       // [64][1024]
    float* h_top  = h1    + 65536;            // [64][1024]
    float* ctx    = h_top + 65536;            // [64][1024]
    float* u_e    = ctx   + 65536;            // [1024]
    float2* ms    = (float2*)(u_e + 1024);    // [250][64] (m, s)

    // 1) LSTM L0 GEMM (A = [emb[tok] ; h0[0]] gathered inline) + u_e side-blocks
    gemm_bf<1,1><<<dim3(32, 9), 512, 0, stream>>>(
        tokens, emb, h0, W_ih, W_hh, 1024, 1024, 4096, gates,
        attn_W, attn_v, u_e);

    // 2) LSTM L0 pointwise + full attention (scores->softmax->context, enc L2-hot)
    lstm_attn<1><<<192, 512, 0, stream>>>(gates, b_ih, b_hh, c0,
                                          h_n, c_n, h1, u_e, enc, ctx);

    // 3) LSTM L1 GEMM (A = [h1 ; h0[1]]) — pure
    gemm_bf<0,0><<<dim3(32, 8), 512, 0, stream>>>(
        nullptr, h1, h0 + BB*HH,
        W_ih + (size_t)4096*1024, W_hh + (size_t)4096*1024, 1024, 1024,
        4096, gates, nullptr, nullptr, nullptr);

    // 4) LSTM L1 pointwise
    lstm_attn<0><<<128, 512, 0, stream>>>(gates, b_ih + 4096, b_hh + 4096, c0 + BB*HH,
                                          h_n + BB*HH, c_n + BB*HH, h_top,
                                          nullptr, nullptr, nullptr);

    // 5) concat GEMM (A = [ctx ; h_top], K=2048) -> catP partials
    gemm_bf<0,0><<<dim3(8, 8), 512, 0, stream>>>(
        nullptr, ctx, h_top, concat_W, nullptr, 1 << 30, 2048,
        1024, catP, nullptr, nullptr, nullptr);

    // 6) out-projection with inline h_c = tanh(concat_b + sum catP) on the A-path
    out_gemm<<<250, 512, 0, stream>>>(catP, concat_b, out_W, out_b, logp, ms);

    // 7) merge partials -> lse, subtract in place
    sub_final<<<dim3(32, 64), 256, 0, stream>>>(logp, ms);
}

// Round 13
// 119.125 us; speedup vs baseline: 1.2541x; 1.2217x over previous
//
#include <hip/hip_runtime.h>
#include <math.h>

#define BB 64
#define HH 1024
#define VV 32000
#define SRC 128
#define SLSTM 8
#define SCAT 8

typedef __attribute__((ext_vector_type(8))) __bf16 bf16x8;
typedef __attribute__((ext_vector_type(8))) unsigned short ushort8;
typedef __attribute__((ext_vector_type(4))) float f32x4;

__device__ __forceinline__ float sigmoidf_(float x){ return 1.f/(1.f+expf(-x)); }

__device__ __forceinline__ unsigned short f2bf(float f){
    union { float f; unsigned u; } v; v.f = f;
    unsigned r = v.u + 0x7FFFu + ((v.u >> 16) & 1u);   // round-to-nearest-even
    return (unsigned short)(r >> 16);
}

__device__ __forceinline__ void cvt8(const float4& x, const float4& y, unsigned short* dst){
    ushort8 s;
    s[0]=f2bf(x.x); s[1]=f2bf(x.y); s[2]=f2bf(x.z); s[3]=f2bf(x.w);
    s[4]=f2bf(y.x); s[5]=f2bf(y.y); s[6]=f2bf(y.z); s[7]=f2bf(y.w);
    *(ushort8*)dst = s;
}

// ---- 64x128 MFMA tile, 512 threads: 2-deep register prefetch, dbuf LDS ----
// One barrier per BK=64 tile; all indexing static (NT template).
template<int NT>
__device__ __forceinline__ void tile_mm(
    const int* tk, const float* A0, const float* A1,
    const float* B0, const float* B1, int K0, int ldb,
    int n0, int kbase,
    unsigned short* AsL, unsigned short* BsL, f32x4* acc)
{
    const int tid = threadIdx.x;
    const int am = tid >> 3, ak = (tid & 7) << 3;
    const int bn = tid >> 2, bk = (tid & 3) << 4;
    const int arow = tk ? tk[am] : am;
    float4 aA[2], bA[4], aB[2], bB[4];

    auto loadG = [&](int t, float4* ar, float4* br){
        int ka = kbase + (t << 6) + ak;
        const float* Ap = (ka < 1024) ? (A0 + (size_t)arow*HH + ka)
                                      : (A1 + (size_t)am*HH + (ka - 1024));
        ar[0] = *(const float4*)(Ap);
        ar[1] = *(const float4*)(Ap + 4);
        int kg = kbase + (t << 6);
        const float* Bp; int kb;
        if (kg < K0) { Bp = B0; kb = kg; } else { Bp = B1; kb = kg - K0; }
        const float* Bq = Bp + (size_t)(n0 + bn) * ldb + kb + bk;
        #pragma unroll
        for (int i = 0; i < 4; ++i) br[i] = *(const float4*)(Bq + i*4);
    };
    auto writeL = [&](int buf, const float4* ar, const float4* br){
        cvt8(ar[0], ar[1], &AsL[buf*4608 + am*72 + ak]);
        cvt8(br[0], br[1], &BsL[buf*9216 + bn*72 + bk]);
        cvt8(br[2], br[3], &BsL[buf*9216 + bn*72 + bk + 8]);
    };

    loadG(0, aA, bA);
    if (NT > 1) loadG(1, aB, bB);
    writeL(0, aA, bA);
    __syncthreads();

    const int lane = tid & 63, w = tid >> 6;
    const int lr = lane >> 4, lc = lane & 15;

    #pragma unroll
    for (int t = 0; t < NT; ++t) {
        const int cur = t & 1;
        if (t + 2 < NT) loadG(t + 2, cur ? aB : aA, cur ? bB : bA);
        #pragma unroll
        for (int ks = 0; ks < 2; ++ks) {
            bf16x8 bF = *(const bf16x8*)&BsL[cur*9216 + (w*16 + lc)*72 + ks*32 + lr*8];
            #pragma unroll
            for (int fm = 0; fm < 4; ++fm) {
                bf16x8 aF = *(const bf16x8*)&AsL[cur*4608 + (fm*16 + lc)*72 + ks*32 + lr*8];
                acc[fm] = __builtin_amdgcn_mfma_f32_16x16x32_bf16(aF, bF, acc[fm], 0, 0, 0);
            }
        }
        if (t + 1 < NT) {
            writeL(cur ^ 1, cur ? aA : aB, cur ? bA : bB);
            __syncthreads();
        }
    }
}

// ============ split-K weight GEMM (+ optional u_e side-blocks), 512 threads ============
// grid = (N/128, 8 [+1 if EXTRA]); kChunk=256; raw partials to C + y*64*N.
// EXTRA==1: y==8, x<16 -> u_e = (attn_W^T v)[1024:2048]
template<int GATHER, int EXTRA>
__global__ __launch_bounds__(512)
void gemm_bf(const int* __restrict__ tokens,
             const float* __restrict__ A0, const float* __restrict__ A1,
             const float* __restrict__ B0, const float* __restrict__ B1,
             int K0, int ldb, int N, float* __restrict__ C,
             const float* __restrict__ xa, const float* __restrict__ xb,
             float* __restrict__ xo)
{
    __shared__ __align__(16) unsigned short As[2*4608];
    __shared__ __align__(16) unsigned short Bs[2*9216];
    const int tid = threadIdx.x;

    if (EXTRA && blockIdx.y >= 8) {
        // u_e[k] = sum_h attn_v[h]*attn_W[h][1024+k]  (h/bias score terms cancel)
        if (blockIdx.x >= 16) return;
        float4 (*red4)[16] = (float4 (*)[16])As;
        int kq = tid & 15, hp = tid >> 4;       // hp 0..31
        int k = 1024 + blockIdx.x*64 + kq*4;
        float4 s4 = {0.f,0.f,0.f,0.f};
        for (int h = hp; h < HH; h += 32) {
            float vh = xb[h];
            float4 wv = *(const float4*)&xa[(size_t)h*2048 + k];
            s4.x = fmaf(vh, wv.x, s4.x); s4.y = fmaf(vh, wv.y, s4.y);
            s4.z = fmaf(vh, wv.z, s4.z); s4.w = fmaf(vh, wv.w, s4.w);
        }
        red4[hp][kq] = s4;
        __syncthreads();
        if (tid < 16) {
            float4 t4 = {0.f,0.f,0.f,0.f};
            #pragma unroll
            for (int i = 0; i < 32; ++i) {
                float4 rv = red4[i][tid];
                t4.x += rv.x; t4.y += rv.y; t4.z += rv.z; t4.w += rv.w;
            }
            *(float4*)&xo[blockIdx.x*64 + tid*4] = t4;
        }
        return;
    }

    f32x4 acc[4] = {};
    const int n0 = blockIdx.x * 128;
    tile_mm<4>(GATHER ? tokens : nullptr, A0, A1, B0, B1, K0, ldb,
               n0, blockIdx.y * 256, As, Bs, acc);
    float* Cp = C + (size_t)blockIdx.y * 64 * N;
    const int lane = tid & 63, w = tid >> 6;
    const int lr = lane >> 4, lc = lane & 15;
    const int n = n0 + w*16 + lc;
    #pragma unroll
    for (int fm = 0; fm < 4; ++fm)
        #pragma unroll
        for (int r = 0; r < 4; ++r)
            Cp[(size_t)(fm*16 + lr*4 + r)*N + n] = acc[fm][r];
}

// ====== out-projection: logits = h_c @ out_W^T + b; fused per-block row (m,s) ======
// 250 blocks x 512 threads; h_c precomputed (cheap dedicated reduce node — R12's
// inline version re-read catP 250x and serialized on tanh: 77 us vs 25 us).
__global__ __launch_bounds__(512)
void out_gemm(const float* __restrict__ A, const float* __restrict__ W,
              const float* __restrict__ bias, float* __restrict__ logits,
              float2* __restrict__ ms)
{
    __shared__ __align__(16) unsigned short As[2*4608];
    __shared__ __align__(16) unsigned short Bs[2*9216];
    __shared__ float wm[8][64], wsum[8][64];
    const int tid = threadIdx.x;
    const int n0 = blockIdx.x * 128;

    f32x4 acc[4] = {};
    tile_mm<16>(nullptr, A, A, W, W, 1 << 30, 1024, n0, 0, As, Bs, acc);

    const int lane = tid & 63, w = tid >> 6;
    const int lr = lane >> 4, lc = lane & 15;
    const int n = n0 + w*16 + lc;
    const float bv = bias[n];
    #pragma unroll
    for (int fm = 0; fm < 4; ++fm) {
        #pragma unroll
        for (int r = 0; r < 4; ++r) {
            float v = acc[fm][r] + bv;
            logits[(size_t)(fm*16 + lr*4 + r)*VV + n] = v;
            float mx = v;
            #pragma unroll
            for (int o = 1; o < 16; o <<= 1) mx = fmaxf(mx, __shfl_xor(mx, o));
            float se = expf(v - mx);
            #pragma unroll
            for (int o = 1; o < 16; o <<= 1) se += __shfl_xor(se, o);
            if (lc == 0) { wm[w][fm*16 + lr*4 + r] = mx;
                           wsum[w][fm*16 + lr*4 + r] = se; }
        }
    }
    __syncthreads();
    if (tid < 64) {
        float M = wm[0][tid];
        #pragma unroll
        for (int i = 1; i < 8; ++i) M = fmaxf(M, wm[i][tid]);
        float S = 0.f;
        #pragma unroll
        for (int i = 0; i < 8; ++i) S += wsum[i][tid] * expf(wm[i][tid] - M);
        ms[blockIdx.x*64 + tid] = make_float2(M, S);
    }
}

// ------- LSTM pointwise (512 thr, 128 blocks) + optional full-attention side-blocks -------
// WITH_ATTN: blocks 128..191 each own batch-row b: scores -> softmax -> context,
// context pass re-reads the block's 512 KB of enc from L2.
template<int WITH_ATTN>
__global__ __launch_bounds__(512)
void lstm_attn(const float* __restrict__ gates,   // [SLSTM][64][4096] raw partials
               const float* __restrict__ bih, const float* __restrict__ bhh,
               const float* __restrict__ c0,
               float* __restrict__ hn, float* __restrict__ cn,
               float* __restrict__ hout,
               const float* __restrict__ u_e, const float* __restrict__ enc,
               float* __restrict__ ctx)
{
    const int bid = blockIdx.x, tid = threadIdx.x;
    if (WITH_ATTN && bid >= 128) {
        __shared__ float wl[SRC];
        const int b = bid - 128;
        const int w = tid >> 6, lane = tid & 63;
        #pragma unroll
        for (int i = 0; i < 16; ++i) {
            int l = w*16 + i;
            const float* e = enc + (size_t)(l*BB + b)*HH;
            float s = 0.f;
            #pragma unroll
            for (int t = 0; t < 16; ++t)
                s = fmaf(u_e[lane + 64*t], e[lane + 64*t], s);
            #pragma unroll
            for (int o = 32; o > 0; o >>= 1) s += __shfl_xor(s, o);
            if (lane == 0) wl[l] = s;
        }
        __syncthreads();
        float m = -INFINITY;
        #pragma unroll 8
        for (int l = 0; l < SRC; ++l) m = fmaxf(m, wl[l]);
        float sum = 0.f;
        #pragma unroll 8
        for (int l = 0; l < SRC; ++l) sum += expf(wl[l] - m);
        float inv = 1.f / sum;
        __syncthreads();
        if (tid < SRC) wl[tid] = expf(wl[tid] - m) * inv;
        __syncthreads();
        float a0 = 0.f, a1 = 0.f;
        for (int l = 0; l < SRC; ++l) {
            const float* e = enc + (size_t)(l*BB + b)*HH;
            float wv = wl[l];
            a0 = fmaf(wv, e[tid], a0);          // L2-hot re-read
            a1 = fmaf(wv, e[tid + 512], a1);
        }
        ctx[b*HH + tid] = a0;
        ctx[b*HH + tid + 512] = a1;
        return;
    }
    int idx = (bid << 9) + tid;          // 0..65535
    int b = idx >> 10, k = idx & 1023;
    const float* g = gates + b*4096;
    float ig = bih[k]        + bhh[k];
    float fg = bih[1024 + k] + bhh[1024 + k];
    float gg = bih[2048 + k] + bhh[2048 + k];
    float og = bih[3072 + k] + bhh[3072 + k];
    #pragma unroll
    for (int s = 0; s < SLSTM; ++s) {
        const float* gs = g + s*BB*4096;
        ig += gs[k];
        fg += gs[1024 + k];
        gg += gs[2048 + k];
        og += gs[3072 + k];
    }
    float c = sigmoidf_(fg)*c0[b*HH + k] + sigmoidf_(ig)*tanhf(gg);
    float h = sigmoidf_(og)*tanhf(c);
    cn[b*HH + k] = c;
    hn[b*HH + k] = h;
    hout[b*HH + k] = h;
}

// ---------------- concat reduce + bias + tanh (SCAT partials) ----------------
__global__ __launch_bounds__(256)
void reduce_tanh(const float* __restrict__ P,   // [SCAT][64][1024]
                 const float* __restrict__ bias, float* __restrict__ out)
{
    int idx = blockIdx.x*256 + threadIdx.x;     // 0..65535
    int n = idx & 1023;
    float s = bias[n];
    #pragma unroll
    for (int si = 0; si < SCAT; ++si) s += P[si*65536 + idx];
    out[idx] = tanhf(s);
}

// ------- merge 250 per-block (m,s) partials -> lse[b]; subtract in place -------
__global__ __launch_bounds__(256)
void sub_final(float* __restrict__ logp, const float2* __restrict__ ms)
{
    __shared__ float2 red[256];
    int b = blockIdx.y;
    float m = -INFINITY, s = 0.f;
    if (threadIdx.x < 250) {
        float2 p = ms[threadIdx.x*64 + b];
        m = p.x; s = p.y;
    }
    red[threadIdx.x] = make_float2(m, s);
    __syncthreads();
    for (int o = 128; o > 0; o >>= 1) {
        if (threadIdx.x < o) {
            float2 a = red[threadIdx.x], c = red[threadIdx.x + o];
            float M = fmaxf(a.x, c.x);
            float S = a.y * expf(a.x - M) + c.y * expf(c.x - M);
            red[threadIdx.x] = make_float2(M, S);
        }
        __syncthreads();
    }
    float lse = red[0].x + logf(red[0].y);
    int i = blockIdx.x*256 + threadIdx.x;       // over 8000 float4
    if (i < 8000) {
        float4* p = (float4*)(logp + (size_t)b*VV);
        float4 v = p[i];
        v.x -= lse; v.y -= lse; v.z -= lse; v.w -= lse;
        p[i] = v;
    }
}

// ================================================================
extern "C" void kernel_launch(void* const* d_in, const int* in_sizes, int n_in,
                              void* d_out, int out_size, void* d_ws, size_t ws_size,
                              hipStream_t stream)
{
    const int*   tokens   = (const int*)  d_in[0];
    const float* h0       = (const float*)d_in[1];
    const float* c0       = (const float*)d_in[2];
    const float* enc      = (const float*)d_in[3];
    const float* emb      = (const float*)d_in[4];
    const float* W_ih     = (const float*)d_in[5];
    const float* W_hh     = (const float*)d_in[6];
    const float* b_ih     = (const float*)d_in[7];
    const float* b_hh     = (const float*)d_in[8];
    const float* attn_W   = (const float*)d_in[9];
    const float* attn_v   = (const float*)d_in[11];
    const float* concat_W = (const float*)d_in[12];
    const float* concat_b = (const float*)d_in[13];
    const float* out_W    = (const float*)d_in[14];
    const float* out_b    = (const float*)d_in[15];

    float* out  = (float*)d_out;
    float* logp = out;                      // [64, 32000]
    float* h_n  = out + (size_t)BB*VV;      // [2, 64, 1024]
    float* c_n  = h_n + 2*BB*HH;            // [2, 64, 1024]

    // workspace layout (floats)
    float* ws     = (float*)d_ws;
    float* gates  = ws;                       // [SLSTM=8][64][4096] partials
    float* catP   = gates + SLSTM*262144;     // [SCAT=8][64][1024] partials
    float* h1     = catP  + SCAT*65536;       // [64][1024]
    float* h_top  = h1    + 65536;            // [64][1024]
    float* ctx    = h_top + 65536;            // [64][1024]
    float* h_c    = ctx   + 65536;            // [64][1024]
    float* u_e    = h_c   + 65536;            // [1024]
    float2* ms    = (float2*)(u_e + 1024);    // [250][64] (m, s)

    // 1) LSTM L0 GEMM (A = [emb[tok] ; h0[0]] gathered inline) + u_e side-blocks
    gemm_bf<1,1><<<dim3(32, 9), 512, 0, stream>>>(
        tokens, emb, h0, W_ih, W_hh, 1024, 1024, 4096, gates,
        attn_W, attn_v, u_e);

    // 2) LSTM L0 pointwise + full attention (scores->softmax->context, enc L2-hot)
    lstm_attn<1><<<192, 512, 0, stream>>>(gates, b_ih, b_hh, c0,
                                          h_n, c_n, h1, u_e, enc, ctx);

    // 3) LSTM L1 GEMM (A = [h1 ; h0[1]]) — pure
    gemm_bf<0,0><<<dim3(32, 8), 512, 0, stream>>>(
        nullptr, h1, h0 + BB*HH,
        W_ih + (size_t)4096*1024, W_hh + (size_t)4096*1024, 1024, 1024,
        4096, gates, nullptr, nullptr, nullptr);

    // 4) LSTM L1 pointwise
    lstm_attn<0><<<128, 512, 0, stream>>>(gates, b_ih + 4096, b_hh + 4096, c0 + BB*HH,
                                          h_n + BB*HH, c_n + BB*HH, h_top,
                                          nullptr, nullptr, nullptr);

    // 5) concat GEMM (A = [ctx ; h_top], K=2048) -> catP partials
    gemm_bf<0,0><<<dim3(8, 8), 512, 0, stream>>>(
        nullptr, ctx, h_top, concat_W, nullptr, 1 << 30, 2048,
        1024, catP, nullptr, nullptr, nullptr);

    // 6) reduce + bias + tanh -> h_c (dedicated node: catP read ONCE, 2 MB)
    reduce_tanh<<<256, 256, 0, stream>>>(catP, concat_b, h_c);

    // 7) out-projection: logits (+bias) direct to d_out + per-block row (m,s) partials
    out_gemm<<<250, 512, 0, stream>>>(h_c, out_W, out_b, logp, ms);

    // 8) merge partials -> lse, subtract in place
    sub_final<<<dim3(32, 64), 256, 0, stream>>>(logp, ms);
}

// Round 14
// 115.986 us; speedup vs baseline: 1.2880x; 1.0271x over previous
//
#include <hip/hip_runtime.h>
#include <math.h>

#define BB 64
#define HH 1024
#define VV 32000
#define SRC 128
#define SLSTM 8
#define SCAT 8

typedef __attribute__((ext_vector_type(8))) __bf16 bf16x8;
typedef __attribute__((ext_vector_type(8))) unsigned short ushort8;
typedef __attribute__((ext_vector_type(4))) float f32x4;

__device__ __forceinline__ float sigmoidf_(float x){ return 1.f/(1.f+expf(-x)); }

__device__ __forceinline__ unsigned short f2bf(float f){
    union { float f; unsigned u; } v; v.f = f;
    unsigned r = v.u + 0x7FFFu + ((v.u >> 16) & 1u);   // round-to-nearest-even
    return (unsigned short)(r >> 16);
}

__device__ __forceinline__ void cvt8(const float4& x, const float4& y, unsigned short* dst){
    ushort8 s;
    s[0]=f2bf(x.x); s[1]=f2bf(x.y); s[2]=f2bf(x.z); s[3]=f2bf(x.w);
    s[4]=f2bf(y.x); s[5]=f2bf(y.y); s[6]=f2bf(y.z); s[7]=f2bf(y.w);
    *(ushort8*)dst = s;
}

// ---- 64x128 MFMA tile, 512 threads: 2-deep register prefetch, dbuf LDS ----
// One barrier per BK=64 tile; all indexing static (NT template).
template<int NT>
__device__ __forceinline__ void tile_mm(
    const int* tk, const float* A0, const float* A1,
    const float* B0, const float* B1, int K0, int ldb,
    int n0, int kbase,
    unsigned short* AsL, unsigned short* BsL, f32x4* acc)
{
    const int tid = threadIdx.x;
    const int am = tid >> 3, ak = (tid & 7) << 3;
    const int bn = tid >> 2, bk = (tid & 3) << 4;
    const int arow = tk ? tk[am] : am;
    float4 aA[2], bA[4], aB[2], bB[4];

    auto loadG = [&](int t, float4* ar, float4* br){
        int ka = kbase + (t << 6) + ak;
        const float* Ap = (ka < 1024) ? (A0 + (size_t)arow*HH + ka)
                                      : (A1 + (size_t)am*HH + (ka - 1024));
        ar[0] = *(const float4*)(Ap);
        ar[1] = *(const float4*)(Ap + 4);
        int kg = kbase + (t << 6);
        const float* Bp; int kb;
        if (kg < K0) { Bp = B0; kb = kg; } else { Bp = B1; kb = kg - K0; }
        const float* Bq = Bp + (size_t)(n0 + bn) * ldb + kb + bk;
        #pragma unroll
        for (int i = 0; i < 4; ++i) br[i] = *(const float4*)(Bq + i*4);
    };
    auto writeL = [&](int buf, const float4* ar, const float4* br){
        cvt8(ar[0], ar[1], &AsL[buf*4608 + am*72 + ak]);
        cvt8(br[0], br[1], &BsL[buf*9216 + bn*72 + bk]);
        cvt8(br[2], br[3], &BsL[buf*9216 + bn*72 + bk + 8]);
    };

    loadG(0, aA, bA);
    if (NT > 1) loadG(1, aB, bB);
    writeL(0, aA, bA);
    __syncthreads();

    const int lane = tid & 63, w = tid >> 6;
    const int lr = lane >> 4, lc = lane & 15;

    #pragma unroll
    for (int t = 0; t < NT; ++t) {
        const int cur = t & 1;
        if (t + 2 < NT) loadG(t + 2, cur ? aB : aA, cur ? bB : bA);
        #pragma unroll
        for (int ks = 0; ks < 2; ++ks) {
            bf16x8 bF = *(const bf16x8*)&BsL[cur*9216 + (w*16 + lc)*72 + ks*32 + lr*8];
            #pragma unroll
            for (int fm = 0; fm < 4; ++fm) {
                bf16x8 aF = *(const bf16x8*)&AsL[cur*4608 + (fm*16 + lc)*72 + ks*32 + lr*8];
                acc[fm] = __builtin_amdgcn_mfma_f32_16x16x32_bf16(aF, bF, acc[fm], 0, 0, 0);
            }
        }
        if (t + 1 < NT) {
            writeL(cur ^ 1, cur ? aA : aB, cur ? bA : bB);
            __syncthreads();
        }
    }
}

// ============ split-K weight GEMM (+ fused side units), 512 threads ============
// grid = (N/128, 8 [+extra]); kChunk=256; raw partials to C + y*64*N.
// EXTRA==1: y==8, x<16 -> u_e = (attn_W^T v)[1024:2048]
// EXTRA==2: y in 8..11 -> fused softmax(scores)+context
template<int GATHER, int EXTRA>
__global__ __launch_bounds__(512)
void gemm_bf(const int* __restrict__ tokens,
             const float* __restrict__ A0, const float* __restrict__ A1,
             const float* __restrict__ B0, const float* __restrict__ B1,
             int K0, int ldb, int N, float* __restrict__ C,
             const float* __restrict__ xa, const float* __restrict__ xb,
             float* __restrict__ xo)
{
    __shared__ __align__(16) unsigned short As[2*4608];
    __shared__ __align__(16) unsigned short Bs[2*9216];
    const int tid = threadIdx.x;

    if (EXTRA && blockIdx.y >= 8) {
        if (EXTRA == 1) {               // u_e[k] = sum_h attn_v[h]*attn_W[h][1024+k]
            if (blockIdx.x >= 16) return;
            float4 (*red4)[16] = (float4 (*)[16])As;
            int kq = tid & 15, hp = tid >> 4;       // hp 0..31
            int k = 1024 + blockIdx.x*64 + kq*4;
            float4 s4 = {0.f,0.f,0.f,0.f};
            for (int h = hp; h < HH; h += 32) {
                float vh = xb[h];
                float4 wv = *(const float4*)&xa[(size_t)h*2048 + k];
                s4.x = fmaf(vh, wv.x, s4.x); s4.y = fmaf(vh, wv.y, s4.y);
                s4.z = fmaf(vh, wv.z, s4.z); s4.w = fmaf(vh, wv.w, s4.w);
            }
            red4[hp][kq] = s4;
            __syncthreads();
            if (tid < 16) {
                float4 t4 = {0.f,0.f,0.f,0.f};
                #pragma unroll
                for (int i = 0; i < 32; ++i) {
                    float4 rv = red4[i][tid];
                    t4.x += rv.x; t4.y += rv.y; t4.z += rv.z; t4.w += rv.w;
                }
                *(float4*)&xo[blockIdx.x*64 + tid*4] = t4;
            }
        } else {                        // smctx: softmax(scores[b,:]) + context
            int sid = (blockIdx.y - 8)*32 + blockIdx.x;   // 0..127
            int b = sid >> 1;
            int h = ((sid & 1) << 9) + tid;
            float* wl = (float*)As;
            if (tid < SRC) wl[tid] = xa[b*SRC + tid];
            __syncthreads();
            float m = -INFINITY;
            #pragma unroll 8
            for (int l = 0; l < SRC; ++l) m = fmaxf(m, wl[l]);
            float sum = 0.f;
            #pragma unroll 8
            for (int l = 0; l < SRC; ++l) sum += expf(wl[l] - m);
            float inv = 1.f / sum;
            __syncthreads();
            if (tid < SRC) wl[tid] = expf(wl[tid] - m) * inv;
            __syncthreads();
            float a = 0.f;
            #pragma unroll 4
            for (int l = 0; l < SRC; ++l)
                a = fmaf(wl[l], xb[(size_t)(l*BB + b)*HH + h], a);
            xo[b*HH + h] = a;
        }
        return;
    }

    f32x4 acc[4] = {};
    const int n0 = blockIdx.x * 128;
    tile_mm<4>(GATHER ? tokens : nullptr, A0, A1, B0, B1, K0, ldb,
               n0, blockIdx.y * 256, As, Bs, acc);
    float* Cp = C + (size_t)blockIdx.y * 64 * N;
    const int lane = tid & 63, w = tid >> 6;
    const int lr = lane >> 4, lc = lane & 15;
    const int n = n0 + w*16 + lc;
    #pragma unroll
    for (int fm = 0; fm < 4; ++fm)
        #pragma unroll
        for (int r = 0; r < 4; ++r)
            Cp[(size_t)(fm*16 + lr*4 + r)*N + n] = acc[fm][r];
}

// ====== out-projection: 500 blocks x 256 thr (2 blocks/CU), 64-wide N tiles ======
// logits = h_c @ out_W^T + b; fused per-block row (max, expsum) partials.
__global__ __launch_bounds__(256)
void out_gemm(const float* __restrict__ A, const float* __restrict__ W,
              const float* __restrict__ bias, float* __restrict__ logits,
              float2* __restrict__ ms)
{
    __shared__ __align__(16) unsigned short As[2*4608];   // 64x72 dbuf
    __shared__ __align__(16) unsigned short Bs[2*4608];   // 64x72 dbuf
    __shared__ float wm[4][64], wsum[4][64];
    const int tid = threadIdx.x;
    const int n0 = blockIdx.x * 64;
    const int r = tid >> 2, q = (tid & 3) << 4;    // row 0..63, 16-float chunk

    f32x4 acc[4] = {};
    float4 aA[4], bA[4], aB[4], bB[4];             // 2-deep staging

    auto loadG = [&](int t, float4* ar, float4* br){
        const float* Ap = A + (size_t)r*HH + (t << 6) + q;
        #pragma unroll
        for (int i = 0; i < 4; ++i) ar[i] = *(const float4*)(Ap + i*4);
        const float* Wp = W + (size_t)(n0 + r)*HH + (t << 6) + q;
        #pragma unroll
        for (int i = 0; i < 4; ++i) br[i] = *(const float4*)(Wp + i*4);
    };
    auto writeL = [&](int buf, const float4* ar, const float4* br){
        cvt8(ar[0], ar[1], &As[buf*4608 + r*72 + q]);
        cvt8(ar[2], ar[3], &As[buf*4608 + r*72 + q + 8]);
        cvt8(br[0], br[1], &Bs[buf*4608 + r*72 + q]);
        cvt8(br[2], br[3], &Bs[buf*4608 + r*72 + q + 8]);
    };

    loadG(0, aA, bA);
    loadG(1, aB, bB);
    writeL(0, aA, bA);
    __syncthreads();

    const int lane = tid & 63, w = tid >> 6;       // 4 waves, wave owns 16 cols
    const int lr = lane >> 4, lc = lane & 15;

    #pragma unroll
    for (int t = 0; t < 16; ++t) {
        const int cur = t & 1;
        if (t + 2 < 16) loadG(t + 2, cur ? aB : aA, cur ? bB : bA);
        #pragma unroll
        for (int ks = 0; ks < 2; ++ks) {
            bf16x8 bF = *(const bf16x8*)&Bs[cur*4608 + (w*16 + lc)*72 + ks*32 + lr*8];
            #pragma unroll
            for (int fm = 0; fm < 4; ++fm) {
                bf16x8 aF = *(const bf16x8*)&As[cur*4608 + (fm*16 + lc)*72 + ks*32 + lr*8];
                acc[fm] = __builtin_amdgcn_mfma_f32_16x16x32_bf16(aF, bF, acc[fm], 0, 0, 0);
            }
        }
        if (t + 1 < 16) {
            writeL(cur ^ 1, cur ? aA : aB, cur ? bA : bB);
            __syncthreads();
        }
    }

    const int n = n0 + w*16 + lc;
    const float bv = bias[n];
    #pragma unroll
    for (int fm = 0; fm < 4; ++fm) {
        #pragma unroll
        for (int r2 = 0; r2 < 4; ++r2) {
            float v = acc[fm][r2] + bv;
            logits[(size_t)(fm*16 + lr*4 + r2)*VV + n] = v;
            float mx = v;
            #pragma unroll
            for (int o = 1; o < 16; o <<= 1) mx = fmaxf(mx, __shfl_xor(mx, o));
            float se = expf(v - mx);
            #pragma unroll
            for (int o = 1; o < 16; o <<= 1) se += __shfl_xor(se, o);
            if (lc == 0) { wm[w][fm*16 + lr*4 + r2] = mx;
                           wsum[w][fm*16 + lr*4 + r2] = se; }
        }
    }
    __syncthreads();
    if (tid < 64) {
        float M = wm[0][tid];
        #pragma unroll
        for (int i = 1; i < 4; ++i) M = fmaxf(M, wm[i][tid]);
        float S = 0.f;
        #pragma unroll
        for (int i = 0; i < 4; ++i) S += wsum[i][tid] * expf(wm[i][tid] - M);
        ms[blockIdx.x*64 + tid] = make_float2(M, S);
    }
}

// ---------------- LSTM pointwise (+ optional fused attention scores) ----------------
template<int WITH_SCORES>
__global__ __launch_bounds__(256)
void lstm_point(const float* __restrict__ gates,   // [SLSTM][64][4096]
                const float* __restrict__ bih, const float* __restrict__ bhh,
                const float* __restrict__ c0,
                float* __restrict__ hn, float* __restrict__ cn,
                float* __restrict__ hout,
                const float* __restrict__ u_e, const float* __restrict__ enc,
                float* __restrict__ scores)
{
    int bid = blockIdx.x;
    if (WITH_SCORES && bid >= 256) {
        // scores[b,l] = u_e . enc[l,b,:]  (h/bias score terms cancel in softmax)
        int g = (bid - 256)*4 + (threadIdx.x >> 6);   // 0..2047, 4 pairs each
        int lane = threadIdx.x & 63;
        #pragma unroll
        for (int q = 0; q < 4; ++q) {
            int p = g*4 + q;
            int b = p >> 7, l = p & 127;
            const float* e = enc + (size_t)(l*BB + b)*HH;
            float s = 0.f;
            #pragma unroll
            for (int t = 0; t < 16; ++t)
                s = fmaf(u_e[lane + 64*t], e[lane + 64*t], s);
            #pragma unroll
            for (int o = 32; o > 0; o >>= 1) s += __shfl_xor(s, o);
            if (lane == 0) scores[b*SRC + l] = s;
        }
        return;
    }
    int idx = bid*256 + threadIdx.x;     // 0..65535
    int b = idx >> 10, k = idx & 1023;
    const float* g = gates + b*4096;
    float ig = bih[k]        + bhh[k];
    float fg = bih[1024 + k] + bhh[1024 + k];
    float gg = bih[2048 + k] + bhh[2048 + k];
    float og = bih[3072 + k] + bhh[3072 + k];
    #pragma unroll
    for (int s = 0; s < SLSTM; ++s) {
        const float* gs = g + s*BB*4096;
        ig += gs[k];
        fg += gs[1024 + k];
        gg += gs[2048 + k];
        og += gs[3072 + k];
    }
    float c = sigmoidf_(fg)*c0[b*HH + k] + sigmoidf_(ig)*tanhf(gg);
    float h = sigmoidf_(og)*tanhf(c);
    cn[b*HH + k] = c;
    hn[b*HH + k] = h;
    hout[b*HH + k] = h;
}

// ---------------- concat reduce + bias + tanh (SCAT partials) ----------------
__global__ __launch_bounds__(256)
void reduce_tanh(const float* __restrict__ P,   // [SCAT][64][1024]
                 const float* __restrict__ bias, float* __restrict__ out)
{
    int idx = blockIdx.x*256 + threadIdx.x;     // 0..65535
    int n = idx & 1023;
    float s = bias[n];
    #pragma unroll
    for (int si = 0; si < SCAT; ++si) s += P[si*65536 + idx];
    out[idx] = tanhf(s);
}

// ------- merge 500 per-block (m,s) partials -> lse[b]; subtract in place -------
__global__ __launch_bounds__(256)
void sub_final(float* __restrict__ logp, const float2* __restrict__ ms)
{
    __shared__ float2 red[256];
    int b = blockIdx.y;
    float m = -1e30f, s = 0.f;
    for (int i = threadIdx.x; i < 500; i += 256) {
        float2 p = ms[i*64 + b];
        float M = fmaxf(m, p.x);
        s = s * expf(m - M) + p.y * expf(p.x - M);
        m = M;
    }
    red[threadIdx.x] = make_float2(m, s);
    __syncthreads();
    for (int o = 128; o > 0; o >>= 1) {
        if (threadIdx.x < o) {
            float2 a = red[threadIdx.x], c = red[threadIdx.x + o];
            float M = fmaxf(a.x, c.x);
            float S = a.y * expf(a.x - M) + c.y * expf(c.x - M);
            red[threadIdx.x] = make_float2(M, S);
        }
        __syncthreads();
    }
    float lse = red[0].x + logf(red[0].y);
    int i = blockIdx.x*256 + threadIdx.x;       // over 8000 float4
    if (i < 8000) {
        float4* p = (float4*)(logp + (size_t)b*VV);
        float4 v = p[i];
        v.x -= lse; v.y -= lse; v.z -= lse; v.w -= lse;
        p[i] = v;
    }
}

// ================================================================
extern "C" void kernel_launch(void* const* d_in, const int* in_sizes, int n_in,
                              void* d_out, int out_size, void* d_ws, size_t ws_size,
                              hipStream_t stream)
{
    const int*   tokens   = (const int*)  d_in[0];
    const float* h0       = (const float*)d_in[1];
    const float* c0       = (const float*)d_in[2];
    const float* enc      = (const float*)d_in[3];
    const float* emb      = (const float*)d_in[4];
    const float* W_ih     = (const float*)d_in[5];
    const float* W_hh     = (const float*)d_in[6];
    const float* b_ih     = (const float*)d_in[7];
    const float* b_hh     = (const float*)d_in[8];
    const float* attn_W   = (const float*)d_in[9];
    const float* attn_v   = (const float*)d_in[11];
    const float* concat_W = (const float*)d_in[12];
    const float* concat_b = (const float*)d_in[13];
    const float* out_W    = (const float*)d_in[14];
    const float* out_b    = (const float*)d_in[15];

    float* out  = (float*)d_out;
    float* logp = out;                      // [64, 32000]
    float* h_n  = out + (size_t)BB*VV;      // [2, 64, 1024]
    float* c_n  = h_n + 2*BB*HH;            // [2, 64, 1024]

    // workspace layout (floats)
    float* ws     = (float*)d_ws;
    float* gates  = ws;                       // [SLSTM=8][64][4096] partials
    float* catP   = gates + SLSTM*262144;     // [SCAT=8][64][1024] partials
    float* h1     = catP  + SCAT*65536;       // [64][1024]
    float* h_top  = h1    + 65536;            // [64][1024]
    float* ctx    = h_top + 65536;            // [64][1024]
    float* h_c    = ctx   + 65536;            // [64][1024]
    float* u_e    = h_c   + 65536;            // [1024]
    float* scores = u_e   + 1024;             // [64][128]
    float2* ms    = (float2*)(scores + 8192); // [500][64] (m, s)

    // 1) LSTM L0 GEMM (A = [emb[tok] ; h0[0]] gathered inline) + u_e side-blocks
    gemm_bf<1,1><<<dim3(32, 9), 512, 0, stream>>>(
        tokens, emb, h0, W_ih, W_hh, 1024, 1024, 4096, gates,
        attn_W, attn_v, u_e);

    // 2) LSTM L0 pointwise + attention scores (independent; fused grid)
    lstm_point<1><<<768, 256, 0, stream>>>(gates, b_ih, b_hh, c0,
                                           h_n, c_n, h1, u_e, enc, scores);

    // 3) LSTM L1 GEMM (A = [h1 ; h0[1]]) + fused softmax/context side-blocks
    gemm_bf<0,2><<<dim3(32, 12), 512, 0, stream>>>(
        nullptr, h1, h0 + BB*HH,
        W_ih + (size_t)4096*1024, W_hh + (size_t)4096*1024, 1024, 1024,
        4096, gates, scores, enc, ctx);

    // 4) LSTM L1 pointwise
    lstm_point<0><<<256, 256, 0, stream>>>(gates, b_ih + 4096, b_hh + 4096, c0 + BB*HH,
                                           h_n + BB*HH, c_n + BB*HH, h_top,
                                           nullptr, nullptr, nullptr);

    // 5) concat GEMM (A = [ctx ; h_top], K=2048) -> catP partials
    gemm_bf<0,0><<<dim3(8, 8), 512, 0, stream>>>(
        nullptr, ctx, h_top, concat_W, nullptr, 1 << 30, 2048,
        1024, catP, nullptr, nullptr, nullptr);

    // 6) reduce + bias + tanh -> h_c (dedicated node: catP read ONCE, 2 MB)
    reduce_tanh<<<256, 256, 0, stream>>>(catP, concat_b, h_c);

    // 7) out-projection: logits (+bias) direct to d_out + per-block row (m,s) partials
    out_gemm<<<500, 256, 0, stream>>>(h_c, out_W, out_b, logp, ms);

    // 8) merge partials -> lse, subtract in place
    sub_final<<<dim3(32, 64), 256, 0, stream>>>(logp, ms);
}

// Round 15
// 109.126 us; speedup vs baseline: 1.3690x; 1.0629x over previous
//
#include <hip/hip_runtime.h>
#include <math.h>

#define BB 64
#define HH 1024
#define VV 32000
#define SRC 128
#define SLSTM 8
#define SCAT 8

typedef __attribute__((ext_vector_type(8))) __bf16 bf16x8;
typedef __attribute__((ext_vector_type(8))) unsigned short ushort8;
typedef __attribute__((ext_vector_type(4))) float f32x4;

__device__ __forceinline__ float sigmoidf_(float x){ return 1.f/(1.f+expf(-x)); }

__device__ __forceinline__ unsigned short f2bf(float f){
    union { float f; unsigned u; } v; v.f = f;
    unsigned r = v.u + 0x7FFFu + ((v.u >> 16) & 1u);   // round-to-nearest-even
    return (unsigned short)(r >> 16);
}

__device__ __forceinline__ void cvt8(const float4& x, const float4& y, unsigned short* dst){
    ushort8 s;
    s[0]=f2bf(x.x); s[1]=f2bf(x.y); s[2]=f2bf(x.z); s[3]=f2bf(x.w);
    s[4]=f2bf(y.x); s[5]=f2bf(y.y); s[6]=f2bf(y.z); s[7]=f2bf(y.w);
    *(ushort8*)dst = s;
}

// ---- 64x128 MFMA tile, 512 threads: 2-deep register prefetch, dbuf LDS ----
// One barrier per BK=64 tile; all indexing static (NT template).
template<int NT>
__device__ __forceinline__ void tile_mm(
    const int* tk, const float* A0, const float* A1,
    const float* B0, const float* B1, int K0, int ldb,
    int n0, int kbase,
    unsigned short* AsL, unsigned short* BsL, f32x4* acc)
{
    const int tid = threadIdx.x;
    const int am = tid >> 3, ak = (tid & 7) << 3;
    const int bn = tid >> 2, bk = (tid & 3) << 4;
    const int arow = tk ? tk[am] : am;
    float4 aA[2], bA[4], aB[2], bB[4];

    auto loadG = [&](int t, float4* ar, float4* br){
        int ka = kbase + (t << 6) + ak;
        const float* Ap = (ka < 1024) ? (A0 + (size_t)arow*HH + ka)
                                      : (A1 + (size_t)am*HH + (ka - 1024));
        ar[0] = *(const float4*)(Ap);
        ar[1] = *(const float4*)(Ap + 4);
        int kg = kbase + (t << 6);
        const float* Bp; int kb;
        if (kg < K0) { Bp = B0; kb = kg; } else { Bp = B1; kb = kg - K0; }
        const float* Bq = Bp + (size_t)(n0 + bn) * ldb + kb + bk;
        #pragma unroll
        for (int i = 0; i < 4; ++i) br[i] = *(const float4*)(Bq + i*4);
    };
    auto writeL = [&](int buf, const float4* ar, const float4* br){
        cvt8(ar[0], ar[1], &AsL[buf*4608 + am*72 + ak]);
        cvt8(br[0], br[1], &BsL[buf*9216 + bn*72 + bk]);
        cvt8(br[2], br[3], &BsL[buf*9216 + bn*72 + bk + 8]);
    };

    loadG(0, aA, bA);
    if (NT > 1) loadG(1, aB, bB);
    writeL(0, aA, bA);
    __syncthreads();

    const int lane = tid & 63, w = tid >> 6;
    const int lr = lane >> 4, lc = lane & 15;

    #pragma unroll
    for (int t = 0; t < NT; ++t) {
        const int cur = t & 1;
        if (t + 2 < NT) loadG(t + 2, cur ? aB : aA, cur ? bB : bA);
        #pragma unroll
        for (int ks = 0; ks < 2; ++ks) {
            bf16x8 bF = *(const bf16x8*)&BsL[cur*9216 + (w*16 + lc)*72 + ks*32 + lr*8];
            #pragma unroll
            for (int fm = 0; fm < 4; ++fm) {
                bf16x8 aF = *(const bf16x8*)&AsL[cur*4608 + (fm*16 + lc)*72 + ks*32 + lr*8];
                acc[fm] = __builtin_amdgcn_mfma_f32_16x16x32_bf16(aF, bF, acc[fm], 0, 0, 0);
            }
        }
        if (t + 1 < NT) {
            writeL(cur ^ 1, cur ? aA : aB, cur ? bA : bB);
            __syncthreads();
        }
    }
}

// ============ split-K weight GEMM (+ fused side units), 512 threads ============
// grid = (N/128, 8 [+extra]); kChunk=256; raw partials to C + y*64*N.
// EXTRA==1: y==8, x<16 -> u_e = (attn_W^T v)[1024:2048]
// EXTRA==2: y in 8..11 -> fused softmax(scores)+context
template<int GATHER, int EXTRA>
__global__ __launch_bounds__(512)
void gemm_bf(const int* __restrict__ tokens,
             const float* __restrict__ A0, const float* __restrict__ A1,
             const float* __restrict__ B0, const float* __restrict__ B1,
             int K0, int ldb, int N, float* __restrict__ C,
             const float* __restrict__ xa, const float* __restrict__ xb,
             float* __restrict__ xo)
{
    __shared__ __align__(16) unsigned short As[2*4608];
    __shared__ __align__(16) unsigned short Bs[2*9216];
    const int tid = threadIdx.x;

    if (EXTRA && blockIdx.y >= 8) {
        if (EXTRA == 1) {               // u_e[k] = sum_h attn_v[h]*attn_W[h][1024+k]
            if (blockIdx.x >= 16) return;
            float4 (*red4)[16] = (float4 (*)[16])As;
            int kq = tid & 15, hp = tid >> 4;       // hp 0..31
            int k = 1024 + blockIdx.x*64 + kq*4;
            float4 s4 = {0.f,0.f,0.f,0.f};
            for (int h = hp; h < HH; h += 32) {
                float vh = xb[h];
                float4 wv = *(const float4*)&xa[(size_t)h*2048 + k];
                s4.x = fmaf(vh, wv.x, s4.x); s4.y = fmaf(vh, wv.y, s4.y);
                s4.z = fmaf(vh, wv.z, s4.z); s4.w = fmaf(vh, wv.w, s4.w);
            }
            red4[hp][kq] = s4;
            __syncthreads();
            if (tid < 16) {
                float4 t4 = {0.f,0.f,0.f,0.f};
                #pragma unroll
                for (int i = 0; i < 32; ++i) {
                    float4 rv = red4[i][tid];
                    t4.x += rv.x; t4.y += rv.y; t4.z += rv.z; t4.w += rv.w;
                }
                *(float4*)&xo[blockIdx.x*64 + tid*4] = t4;
            }
        } else {                        // smctx: softmax(scores[b,:]) + context
            int sid = (blockIdx.y - 8)*32 + blockIdx.x;   // 0..127
            int b = sid >> 1;
            int h = ((sid & 1) << 9) + tid;
            float* wl = (float*)As;
            if (tid < SRC) wl[tid] = xa[b*SRC + tid];
            __syncthreads();
            float m = -INFINITY;
            #pragma unroll 8
            for (int l = 0; l < SRC; ++l) m = fmaxf(m, wl[l]);
            float sum = 0.f;
            #pragma unroll 8
            for (int l = 0; l < SRC; ++l) sum += expf(wl[l] - m);
            float inv = 1.f / sum;
            __syncthreads();
            if (tid < SRC) wl[tid] = expf(wl[tid] - m) * inv;
            __syncthreads();
            float a = 0.f;
            #pragma unroll 4
            for (int l = 0; l < SRC; ++l)
                a = fmaf(wl[l], xb[(size_t)(l*BB + b)*HH + h], a);
            xo[b*HH + h] = a;
        }
        return;
    }

    f32x4 acc[4] = {};
    const int n0 = blockIdx.x * 128;
    tile_mm<4>(GATHER ? tokens : nullptr, A0, A1, B0, B1, K0, ldb,
               n0, blockIdx.y * 256, As, Bs, acc);
    float* Cp = C + (size_t)blockIdx.y * 64 * N;
    const int lane = tid & 63, w = tid >> 6;
    const int lr = lane >> 4, lc = lane & 15;
    const int n = n0 + w*16 + lc;
    #pragma unroll
    for (int fm = 0; fm < 4; ++fm)
        #pragma unroll
        for (int r = 0; r < 4; ++r)
            Cp[(size_t)(fm*16 + lr*4 + r)*N + n] = acc[fm][r];
}

// ====== out-projection: 250 blocks x 512 thr, 128-wide tiles, depth-3 B prefetch ======
// logits = h_c @ out_W^T + b; fused per-block row (max, expsum) partials.
__global__ __launch_bounds__(512)
void out_gemm(const float* __restrict__ A, const float* __restrict__ W,
              const float* __restrict__ bias, float* __restrict__ logits,
              float2* __restrict__ ms)
{
    __shared__ __align__(16) unsigned short As[2*4608];
    __shared__ __align__(16) unsigned short Bs[2*9216];
    __shared__ float wm[8][64], wsum[8][64];
    const int tid = threadIdx.x;
    const int n0 = blockIdx.x * 128;
    const int am = tid >> 3, ak = (tid & 7) << 3;   // A: 64 rows x 8-float chunks
    const int bn = tid >> 2, bk = (tid & 3) << 4;   // B: 128 rows x 16-float chunks

    f32x4 acc[4] = {};
    float4 aA[2], aB[2];                 // A staging: depth 2 (L2/L3-hot, tiny)
    float4 bA[4], bB[4], bC[4];          // B staging: depth 3 (HBM stream)

    auto loadA = [&](int t, float4* ar){
        const float* Ap = A + (size_t)am*HH + (t << 6) + ak;
        ar[0] = *(const float4*)(Ap);
        ar[1] = *(const float4*)(Ap + 4);
    };
    auto loadB = [&](int t, float4* br){
        const float* Wp = W + (size_t)(n0 + bn)*HH + (t << 6) + bk;
        #pragma unroll
        for (int i = 0; i < 4; ++i) br[i] = *(const float4*)(Wp + i*4);
    };
    auto writeL = [&](int buf, const float4* ar, const float4* br){
        cvt8(ar[0], ar[1], &As[buf*4608 + am*72 + ak]);
        cvt8(br[0], br[1], &Bs[buf*9216 + bn*72 + bk]);
        cvt8(br[2], br[3], &Bs[buf*9216 + bn*72 + bk + 8]);
    };

    loadA(0, aA); loadA(1, aB);
    loadB(0, bA); loadB(1, bB); loadB(2, bC);
    writeL(0, aA, bA);
    __syncthreads();

    const int lane = tid & 63, w = tid >> 6;
    const int lr = lane >> 4, lc = lane & 15;

    #pragma unroll
    for (int t = 0; t < 16; ++t) {
        const int cur = t & 1;
        // refill the sets freed when tile t went to LDS (end of iter t-1)
        if (t + 3 < 16) loadB(t + 3, (t % 3 == 0) ? bA : (t % 3 == 1) ? bB : bC);
        if (t + 2 < 16) loadA(t + 2, cur ? aB : aA);
        #pragma unroll
        for (int ks = 0; ks < 2; ++ks) {
            bf16x8 bF = *(const bf16x8*)&Bs[cur*9216 + (w*16 + lc)*72 + ks*32 + lr*8];
            #pragma unroll
            for (int fm = 0; fm < 4; ++fm) {
                bf16x8 aF = *(const bf16x8*)&As[cur*4608 + (fm*16 + lc)*72 + ks*32 + lr*8];
                acc[fm] = __builtin_amdgcn_mfma_f32_16x16x32_bf16(aF, bF, acc[fm], 0, 0, 0);
            }
        }
        if (t + 1 < 16) {
            // tile t+1 lives in set (t+1)%2 of A and (t+1)%3 of B
            writeL(cur ^ 1, cur ? aA : aB,
                   ((t + 1) % 3 == 0) ? bA : ((t + 1) % 3 == 1) ? bB : bC);
            __syncthreads();
        }
    }

    const int n = n0 + w*16 + lc;
    const float bv = bias[n];
    #pragma unroll
    for (int fm = 0; fm < 4; ++fm) {
        #pragma unroll
        for (int r = 0; r < 4; ++r) {
            float v = acc[fm][r] + bv;
            logits[(size_t)(fm*16 + lr*4 + r)*VV + n] = v;
            float mx = v;
            #pragma unroll
            for (int o = 1; o < 16; o <<= 1) mx = fmaxf(mx, __shfl_xor(mx, o));
            float se = expf(v - mx);
            #pragma unroll
            for (int o = 1; o < 16; o <<= 1) se += __shfl_xor(se, o);
            if (lc == 0) { wm[w][fm*16 + lr*4 + r] = mx;
                           wsum[w][fm*16 + lr*4 + r] = se; }
        }
    }
    __syncthreads();
    if (tid < 64) {
        float M = wm[0][tid];
        #pragma unroll
        for (int i = 1; i < 8; ++i) M = fmaxf(M, wm[i][tid]);
        float S = 0.f;
        #pragma unroll
        for (int i = 0; i < 8; ++i) S += wsum[i][tid] * expf(wm[i][tid] - M);
        ms[blockIdx.x*64 + tid] = make_float2(M, S);
    }
}

// ---------------- LSTM pointwise (+ optional fused attention scores) ----------------
template<int WITH_SCORES>
__global__ __launch_bounds__(256)
void lstm_point(const float* __restrict__ gates,   // [SLSTM][64][4096]
                const float* __restrict__ bih, const float* __restrict__ bhh,
                const float* __restrict__ c0,
                float* __restrict__ hn, float* __restrict__ cn,
                float* __restrict__ hout,
                const float* __restrict__ u_e, const float* __restrict__ enc,
                float* __restrict__ scores)
{
    int bid = blockIdx.x;
    if (WITH_SCORES && bid >= 256) {
        // scores[b,l] = u_e . enc[l,b,:]  (h/bias score terms cancel in softmax)
        int g = (bid - 256)*4 + (threadIdx.x >> 6);   // 0..2047, 4 pairs each
        int lane = threadIdx.x & 63;
        #pragma unroll
        for (int q = 0; q < 4; ++q) {
            int p = g*4 + q;
            int b = p >> 7, l = p & 127;
            const float* e = enc + (size_t)(l*BB + b)*HH;
            float s = 0.f;
            #pragma unroll
            for (int t = 0; t < 16; ++t)
                s = fmaf(u_e[lane + 64*t], e[lane + 64*t], s);
            #pragma unroll
            for (int o = 32; o > 0; o >>= 1) s += __shfl_xor(s, o);
            if (lane == 0) scores[b*SRC + l] = s;
        }
        return;
    }
    int idx = bid*256 + threadIdx.x;     // 0..65535
    int b = idx >> 10, k = idx & 1023;
    const float* g = gates + b*4096;
    float ig = bih[k]        + bhh[k];
    float fg = bih[1024 + k] + bhh[1024 + k];
    float gg = bih[2048 + k] + bhh[2048 + k];
    float og = bih[3072 + k] + bhh[3072 + k];
    #pragma unroll
    for (int s = 0; s < SLSTM; ++s) {
        const float* gs = g + s*BB*4096;
        ig += gs[k];
        fg += gs[1024 + k];
        gg += gs[2048 + k];
        og += gs[3072 + k];
    }
    float c = sigmoidf_(fg)*c0[b*HH + k] + sigmoidf_(ig)*tanhf(gg);
    float h = sigmoidf_(og)*tanhf(c);
    cn[b*HH + k] = c;
    hn[b*HH + k] = h;
    hout[b*HH + k] = h;
}

// ---------------- concat reduce + bias + tanh (SCAT partials) ----------------
__global__ __launch_bounds__(256)
void reduce_tanh(const float* __restrict__ P,   // [SCAT][64][1024]
                 const float* __restrict__ bias, float* __restrict__ out)
{
    int idx = blockIdx.x*256 + threadIdx.x;     // 0..65535
    int n = idx & 1023;
    float s = bias[n];
    #pragma unroll
    for (int si = 0; si < SCAT; ++si) s += P[si*65536 + idx];
    out[idx] = tanhf(s);
}

// ------- merge 250 per-block (m,s) partials -> lse[b]; subtract in place -------
__global__ __launch_bounds__(256)
void sub_final(float* __restrict__ logp, const float2* __restrict__ ms)
{
    __shared__ float2 red[256];
    int b = blockIdx.y;
    float m = -INFINITY, s = 0.f;
    if (threadIdx.x < 250) {
        float2 p = ms[threadIdx.x*64 + b];
        m = p.x; s = p.y;
    }
    red[threadIdx.x] = make_float2(m, s);
    __syncthreads();
    for (int o = 128; o > 0; o >>= 1) {
        if (threadIdx.x < o) {
            float2 a = red[threadIdx.x], c = red[threadIdx.x + o];
            float M = fmaxf(a.x, c.x);
            float S = a.y * expf(a.x - M) + c.y * expf(c.x - M);
            red[threadIdx.x] = make_float2(M, S);
        }
        __syncthreads();
    }
    float lse = red[0].x + logf(red[0].y);
    int i = blockIdx.x*256 + threadIdx.x;       // over 8000 float4
    if (i < 8000) {
        float4* p = (float4*)(logp + (size_t)b*VV);
        float4 v = p[i];
        v.x -= lse; v.y -= lse; v.z -= lse; v.w -= lse;
        p[i] = v;
    }
}

// ================================================================
extern "C" void kernel_launch(void* const* d_in, const int* in_sizes, int n_in,
                              void* d_out, int out_size, void* d_ws, size_t ws_size,
                              hipStream_t stream)
{
    const int*   tokens   = (const int*)  d_in[0];
    const float* h0       = (const float*)d_in[1];
    const float* c0       = (const float*)d_in[2];
    const float* enc      = (const float*)d_in[3];
    const float* emb      = (const float*)d_in[4];
    const float* W_ih     = (const float*)d_in[5];
    const float* W_hh     = (const float*)d_in[6];
    const float* b_ih     = (const float*)d_in[7];
    const float* b_hh     = (const float*)d_in[8];
    const float* attn_W   = (const float*)d_in[9];
    const float* attn_v   = (const float*)d_in[11];
    const float* concat_W = (const float*)d_in[12];
    const float* concat_b = (const float*)d_in[13];
    const float* out_W    = (const float*)d_in[14];
    const float* out_b    = (const float*)d_in[15];

    float* out  = (float*)d_out;
    float* logp = out;                      // [64, 32000]
    float* h_n  = out + (size_t)BB*VV;      // [2, 64, 1024]
    float* c_n  = h_n + 2*BB*HH;            // [2, 64, 1024]

    // workspace layout (floats)
    float* ws     = (float*)d_ws;
    float* gates  = ws;                       // [SLSTM=8][64][4096] partials
    float* catP   = gates + SLSTM*262144;     // [SCAT=8][64][1024] partials
    float* h1     = catP  + SCAT*65536;       // [64][1024]
    float* h_top  = h1    + 65536;            // [64][1024]
    float* ctx    = h_top + 65536;            // [64][1024]
    float* h_c    = ctx   + 65536;            // [64][1024]
    float* u_e    = h_c   + 65536;            // [1024]
    float* scores = u_e   + 1024;             // [64][128]
    float2* ms    = (float2*)(scores + 8192); // [250][64] (m, s)

    // 1) LSTM L0 GEMM (A = [emb[tok] ; h0[0]] gathered inline) + u_e side-blocks
    gemm_bf<1,1><<<dim3(32, 9), 512, 0, stream>>>(
        tokens, emb, h0, W_ih, W_hh, 1024, 1024, 4096, gates,
        attn_W, attn_v, u_e);

    // 2) LSTM L0 pointwise + attention scores (independent; fused grid)
    lstm_point<1><<<768, 256, 0, stream>>>(gates, b_ih, b_hh, c0,
                                           h_n, c_n, h1, u_e, enc, scores);

    // 3) LSTM L1 GEMM (A = [h1 ; h0[1]]) + fused softmax/context side-blocks
    gemm_bf<0,2><<<dim3(32, 12), 512, 0, stream>>>(
        nullptr, h1, h0 + BB*HH,
        W_ih + (size_t)4096*1024, W_hh + (size_t)4096*1024, 1024, 1024,
        4096, gates, scores, enc, ctx);

    // 4) LSTM L1 pointwise
    lstm_point<0><<<256, 256, 0, stream>>>(gates, b_ih + 4096, b_hh + 4096, c0 + BB*HH,
                                           h_n + BB*HH, c_n + BB*HH, h_top,
                                           nullptr, nullptr, nullptr);

    // 5) concat GEMM (A = [ctx ; h_top], K=2048) -> catP partials
    gemm_bf<0,0><<<dim3(8, 8), 512, 0, stream>>>(
        nullptr, ctx, h_top, concat_W, nullptr, 1 << 30, 2048,
        1024, catP, nullptr, nullptr, nullptr);

    // 6) reduce + bias + tanh -> h_c (dedicated node: catP read ONCE, 2 MB)
    reduce_tanh<<<256, 256, 0, stream>>>(catP, concat_b, h_c);

    // 7) out-projection: logits (+bias) direct to d_out + per-block row (m,s) partials
    out_gemm<<<250, 512, 0, stream>>>(h_c, out_W, out_b, logp, ms);

    // 8) merge partials -> lse, subtract in place
    sub_final<<<dim3(32, 64), 256, 0, stream>>>(logp, ms);
}